// Round 6
// baseline (558.052 us; speedup 1.0000x reference)
//
#include <hip/hip_runtime.h>
#include <math.h>

#define EPS 1e-5f

constexpr int NB      = 16;
constexpr int L       = 1024;
constexpr int DM      = 128;
constexpr int DI      = 256;
constexpr int DS      = 64;
constexpr int NH      = 8;
constexpr int DPROJ   = 648;   // 2*DI + 2*DS + NH
constexpr int CDIM    = 384;   // DI + 2*DS
constexpr int EPAD    = 656;   // DPROJ padded to 41*16

typedef __attribute__((ext_vector_type(8))) short short8v;
typedef __attribute__((ext_vector_type(4))) short short4v;
typedef __attribute__((ext_vector_type(4))) float f32x4;
typedef unsigned short ushort_t;

__device__ __forceinline__ float silu_f(float x){ return x / (1.f + expf(-x)); }
__device__ __forceinline__ ushort_t f2bf(float f){
  union { float f; unsigned int u; } v; v.f = f;
  unsigned int r = v.u + 0x7FFF + ((v.u >> 16) & 1);
  return (ushort_t)(r >> 16);
}
__device__ __forceinline__ float bf2f(ushort_t u){
  union { float f; unsigned int u; } v; v.u = ((unsigned int)u) << 16;
  return v.f;
}
__device__ __forceinline__ short8v pack8(float4 a, float4 b){
  short8v v;
  v[0]=(short)f2bf(a.x); v[1]=(short)f2bf(a.y); v[2]=(short)f2bf(a.z); v[3]=(short)f2bf(a.w);
  v[4]=(short)f2bf(b.x); v[5]=(short)f2bf(b.y); v[6]=(short)f2bf(b.z); v[7]=(short)f2bf(b.w);
  return v;
}

// ---------------- weight conversion / folding (runs once per launch) ----------------
__global__ __launch_bounds__(256) void k_cvt(const float* __restrict__ in_w,
    const float* __restrict__ ln_g, const float* __restrict__ ln_b,
    const float* __restrict__ out_w, const float* __restrict__ nw,
    const float* __restrict__ patch_w, const float* __restrict__ w1,
    ushort_t* __restrict__ inwb, ushort_t* __restrict__ owb,
    ushort_t* __restrict__ pwb, float* __restrict__ biasin,
    ushort_t* __restrict__ w1b){
  const int R1 = 4 * EPAD * 128, R2 = 4 * 128 * 256, R3 = 128 * 768, R4 = 4 * EPAD, R5 = 64 * 128;
  int i = blockIdx.x * 256 + threadIdx.x;
  if (i < R1) {
    int ly = i / (EPAD * 128), rem = i % (EPAD * 128), e = rem >> 7, d = rem & 127;
    float v = 0.f;
    if (e < DPROJ) v = in_w[((size_t)ly * DPROJ + e) * 128 + d] * ln_g[ly * 128 + d];
    inwb[i] = f2bf(v);
    return;
  }
  i -= R1;
  if (i < R2) {
    int ly = i >> 15, rem = i & 32767, e = rem & 255;
    owb[i] = f2bf(out_w[i] * nw[ly * 256 + e]);
    return;
  }
  i -= R2;
  if (i < R3) { pwb[i] = f2bf(patch_w[i]); return; }
  i -= R3;
  if (i < R4) {
    int ly = i / EPAD, e = i % EPAD;
    float s = 0.f;
    if (e < DPROJ) {
      const float* r = in_w + ((size_t)ly * DPROJ + e) * 128;
      const float* b = ln_b + ly * 128;
      for (int d = 0; d < 128; ++d) s += r[d] * b[d];
    }
    biasin[i] = s;
    return;
  }
  i -= R4;
  if (i < R5) w1b[i] = f2bf(w1[i]);
}

// ---------------- patch embed (MFMA) + pos layernorm ----------------
__global__ __launch_bounds__(256) void k_patch(const float* __restrict__ x,
    const ushort_t* __restrict__ pwb, const float* __restrict__ pb,
    const float* __restrict__ pg, const float* __restrict__ pbe,
    float* __restrict__ tok){
  __shared__ ushort_t Al[64 * 128];
  __shared__ ushort_t Bl[128 * 128];
  __shared__ float spb[128], spg[128], spe[128];
  const int m0 = blockIdx.x * 64;
  const int tid = threadIdx.x;
  char* Ab = (char*)Al; char* Bb = (char*)Bl;
  if (tid < 128) { spb[tid] = pb[tid]; spg[tid] = pg[tid]; spe[tid] = pbe[tid]; }
  const int w = tid >> 6, l = tid & 63, lr = l & 15, lgp = l >> 4;
  f32x4 acc[8];
#pragma unroll
  for (int nt = 0; nt < 8; ++nt) acc[nt] = (f32x4){0.f, 0.f, 0.f, 0.f};
  for (int kc = 0; kc < 6; ++kc) {
    __syncthreads();
    for (int idx = tid; idx < 128 * 16; idx += 256) {
      int n = idx >> 4, ch = idx & 15;
      short8v v = *(const short8v*)(pwb + (size_t)n * 768 + kc * 128 + (ch << 3));
      *(short8v*)(Bb + n * 256 + ((ch * 16) ^ ((n & 7) << 4))) = v;
    }
    {
      const int c = kc >> 1;
      for (int i = tid; i < 1024; i += 256) {
        int t = i >> 4, p = (i >> 1) & 7, o = i & 1;
        int T = m0 + t, bb = T >> 10, tl = T & 1023, hp = tl >> 5, wp = tl & 31;
        const float* src = x + (((size_t)(bb * 3 + c) * 512 + hp * 16 + ((kc & 1) << 3) + p) * 512
                                + wp * 16 + o * 8);
        float4 f0 = *(const float4*)src;
        float4 f1 = *(const float4*)(src + 4);
        short8v v = pack8(f0, f1);
        int kk = p * 16 + o * 8;
        *(short8v*)(Ab + t * 256 + ((kk * 2) ^ ((t & 7) << 4))) = v;
      }
    }
    __syncthreads();
    short8v a[4];
#pragma unroll
    for (int ks = 0; ks < 4; ++ks)
      a[ks] = *(const short8v*)(Ab + (16 * w + lr) * 256 + ((ks * 64 + lgp * 16) ^ ((lr & 7) << 4)));
#pragma unroll
    for (int nt = 0; nt < 8; ++nt) {
#pragma unroll
      for (int ks = 0; ks < 4; ++ks) {
        short8v b = *(const short8v*)(Bb + (nt * 16 + lr) * 256 + ((ks * 64 + lgp * 16) ^ ((lr & 7) << 4)));
        acc[nt] = __builtin_amdgcn_mfma_f32_16x16x32_bf16(a[ks], b, acc[nt], 0, 0, 0);
      }
    }
  }
  float s4[4] = {0,0,0,0}, q4[4] = {0,0,0,0};
#pragma unroll
  for (int nt = 0; nt < 8; ++nt) {
    const float bb = spb[nt * 16 + lr];
#pragma unroll
    for (int r = 0; r < 4; ++r) { float v = acc[nt][r] + bb; s4[r] += v; q4[r] += v * v; }
  }
#pragma unroll
  for (int r = 0; r < 4; ++r) {
    for (int off = 1; off < 16; off <<= 1) {
      s4[r] += __shfl_xor(s4[r], off, 16);
      q4[r] += __shfl_xor(q4[r], off, 16);
    }
  }
#pragma unroll
  for (int r = 0; r < 4; ++r) {
    float mean = s4[r] * (1.f / 128.f);
    float var  = q4[r] * (1.f / 128.f) - mean * mean;
    float rstd = rsqrtf(var + EPS);
    const size_t row = (size_t)(m0 + 16 * w + lgp * 4 + r) * 128;
#pragma unroll
    for (int nt = 0; nt < 8; ++nt) {
      int col = nt * 16 + lr;
      float v = acc[nt][r] + spb[col];
      tok[row + col] = (v - mean) * rstd * spg[col] + spe[col];
    }
  }
}

// ---------------- fused layernorm + in_proj (MFMA, M=128 tile) ----------------
__global__ __launch_bounds__(256) void k_inproj(const float* __restrict__ tok,
    const ushort_t* __restrict__ inwb, const float* __restrict__ biasin,
    float* __restrict__ zx){
  __shared__ ushort_t Al[128 * 128];
  __shared__ ushort_t Bl[176 * 128];
  __shared__ float sBias[176];
  const int blk = blockIdx.x;
  const int mb = blk >> 2, nb = blk & 3;
  const int m0 = mb << 7, n0 = nb * 176;
  const int NT = (nb == 3) ? 128 : 176;
  const int tid = threadIdx.x;
  char* Ab = (char*)Al; char* Bb = (char*)Bl;
  for (int idx = tid; idx < (NT << 4); idx += 256) {
    int row = idx >> 4, ch = idx & 15;
    short8v v = *(const short8v*)(inwb + ((size_t)(n0 + row) << 7) + (ch << 3));
    *(short8v*)(Bb + row * 256 + ((ch * 16) ^ ((row & 7) << 4))) = v;
  }
  for (int idx = tid; idx < NT; idx += 256) sBias[idx] = biasin[n0 + idx];
  for (int rp = 0; rp < 2; ++rp) {
    const int r = (rp << 6) + (tid >> 2), t4 = tid & 3;
    const float* src = tok + (((size_t)(m0 + r)) << 7) + t4 * 32;
    float v[32];
    float s = 0.f, sq = 0.f;
#pragma unroll
    for (int k = 0; k < 8; ++k) {
      float4 f = *(const float4*)(src + 4 * k);
      v[4*k] = f.x; v[4*k+1] = f.y; v[4*k+2] = f.z; v[4*k+3] = f.w;
      s += f.x + f.y + f.z + f.w;
      sq += f.x*f.x + f.y*f.y + f.z*f.z + f.w*f.w;
    }
    s  += __shfl_xor(s, 1, 4);  s  += __shfl_xor(s, 2, 4);
    sq += __shfl_xor(sq, 1, 4); sq += __shfl_xor(sq, 2, 4);
    float mean = s * (1.f / 128.f);
    float var  = sq * (1.f / 128.f) - mean * mean;
    float rstd = rsqrtf(var + EPS);
#pragma unroll
    for (int k = 0; k < 4; ++k) {
      short8v o;
#pragma unroll
      for (int e = 0; e < 8; ++e) o[e] = (short)f2bf((v[8*k + e] - mean) * rstd);
      *(short8v*)(Ab + r * 256 + ((t4 * 64 + 16 * k) ^ ((r & 7) << 4))) = o;
    }
  }
  __syncthreads();
  const int w = tid >> 6, l = tid & 63, lr = l & 15, lgp = l >> 4;
  const int xsl = (lr & 7) << 4;
  short8v a[2][4];
#pragma unroll
  for (int mi = 0; mi < 2; ++mi) {
    const int mt = w + mi * 4;
#pragma unroll
    for (int ks = 0; ks < 4; ++ks)
      a[mi][ks] = *(const short8v*)(Ab + (16 * mt + lr) * 256 + ((ks * 64 + lgp * 16) ^ xsl));
  }
  const int NTT = NT >> 4;
  for (int nt = 0; nt < NTT; ++nt) {
    f32x4 acc0 = (f32x4){0.f, 0.f, 0.f, 0.f};
    f32x4 acc1 = (f32x4){0.f, 0.f, 0.f, 0.f};
#pragma unroll
    for (int ks = 0; ks < 4; ++ks) {
      short8v b = *(const short8v*)(Bb + (nt * 16 + lr) * 256 + ((ks * 64 + lgp * 16) ^ xsl));
      acc0 = __builtin_amdgcn_mfma_f32_16x16x32_bf16(a[0][ks], b, acc0, 0, 0, 0);
      acc1 = __builtin_amdgcn_mfma_f32_16x16x32_bf16(a[1][ks], b, acc1, 0, 0, 0);
    }
    const int col = n0 + nt * 16 + lr;
    if (col < DPROJ) {
      const float bias = sBias[nt * 16 + lr];
#pragma unroll
      for (int r = 0; r < 4; ++r) {
        zx[((size_t)(m0 + 16 * w       + lgp * 4 + r)) * DPROJ + col] = acc0[r] + bias;
        zx[((size_t)(m0 + 16 * (w + 4) + lgp * 4 + r)) * DPROJ + col] = acc1[r] + bias;
      }
    }
  }
}

// ---------------- causal depthwise conv + silu (LDS-tiled, bf16 out) ----------------
constexpr int CONVC = 192;
__global__ __launch_bounds__(256) void k_conv(const float* __restrict__ zx,
    const float* __restrict__ cw, const float* __restrict__ cb, ushort_t* __restrict__ xc){
  __shared__ float st[67][CONVC];
  __shared__ float swt[CONVC][4];
  __shared__ float sbias[CONVC];
  const int blk = blockIdx.x;
  const int cg = blk & 1, tile = (blk >> 1) & 15, b = blk >> 5;
  const int l0 = tile << 6, ch0 = cg * CONVC;
  const int tid = threadIdx.x;
  for (int i = tid; i < CONVC; i += 256) {
    float4 wv = *(const float4*)(cw + (size_t)(ch0 + i) * 4);
    swt[i][0] = wv.x; swt[i][1] = wv.y; swt[i][2] = wv.z; swt[i][3] = wv.w;
    sbias[i] = cb[ch0 + i];
  }
  for (int i = tid; i < 67 * 48; i += 256) {
    int rr = i / 48, q4 = i % 48;
    int lrow = l0 + rr - 3;
    float4 v = make_float4(0.f, 0.f, 0.f, 0.f);
    if (lrow >= 0) v = *(const float4*)(zx + ((size_t)(b << 10) + lrow) * DPROJ + DI + ch0 + q4 * 4);
    *(float4*)(&st[rr][q4 * 4]) = v;
  }
  __syncthreads();
  for (int i = tid; i < 64 * 48; i += 256) {
    int t = i / 48, g = i % 48;
    short4v ov;
#pragma unroll
    for (int j = 0; j < 4; ++j) {
      int c2 = g * 4 + j;
      float acc = sbias[c2] + st[t][c2] * swt[c2][0] + st[t+1][c2] * swt[c2][1]
                + st[t+2][c2] * swt[c2][2] + st[t+3][c2] * swt[c2][3];
      ov[j] = (short)f2bf(silu_f(acc));
    }
    *(short4v*)(xc + ((size_t)(b << 10) + l0 + t) * CDIM + ch0 + g * 4) = ov;
  }
}

// ---------------- fused SSD: dt + chunk-state + inter-chunk scan + outputs ----------------
// grid NB*NH*2 = 256 blocks: (b, h, p-half). 256 threads (4 waves).
// State h[p(16)][n(64)] lives in registers as one MFMA C-fragment per thread.
// Per chunk: G = C.B^T (MFMA); S = (coef.X)^T . B (MFMA, via scaled-B^T);
// h = Ac*h + S; Y = [W | Pt*C](64x128) @ [X^T ; h0](16x128)^T (MFMA K=128).
__global__ __launch_bounds__(256) void k_ssd(const ushort_t* __restrict__ xcb,
    const float* __restrict__ zx, const float* __restrict__ dtbias,
    const float* __restrict__ Alog, const float* __restrict__ Dsk,
    ushort_t* __restrict__ ys){
  __shared__ ushort_t sBm[64 * 64];    // B [s][n]   8 KB
  __shared__ ushort_t sCm[64 * 64];    // C [t][n]   8 KB
  __shared__ ushort_t sBT[64 * 64];    // coef*B^T [n][s] 8 KB
  __shared__ ushort_t sAW[64 * 128];   // [t][ W(k<64) | Pt*C(k>=64) ] 16 KB
  __shared__ ushort_t sBX[16 * 128];   // [p][ X^T(k<64) | h0(k>=64) ] 4 KB
  __shared__ float sdt[64], slc[64];
  const int blk = blockIdx.x;
  const int ph = blk & 1, h = (blk >> 1) & 7, b = blk >> 4;
  const int tid = threadIdx.x;
  const int w = tid >> 6, l = tid & 63, lr = l & 15, lgp = l >> 4;
  char* pB = (char*)sBm; char* pC = (char*)sCm; char* pT = (char*)sBT;
  char* pA = (char*)sAW; char* pX = (char*)sBX;
  const int srow = tid >> 2, sq = tid & 3;
  const int xs = (srow & 7) << 4;
  const int xsl = (lr & 7) << 4;
  const float dtb_h = dtbias[h];
  const float nA = -expf(Alog[h]);
  const float dsk = Dsk[h];
  const size_t base_b = (size_t)(b << 10);
  float hfrag[4] = {0.f, 0.f, 0.f, 0.f};
  // prefetch chunk 0
  short8v pb0, pb1, pc0, pc1; short4v px; float dtraw = 0.f;
  {
    const ushort_t* xr = xcb + (base_b + srow) * CDIM;
    pb0 = *(const short8v*)(xr + 256 + sq * 16);
    pb1 = *(const short8v*)(xr + 256 + sq * 16 + 8);
    pc0 = *(const short8v*)(xr + 320 + sq * 16);
    pc1 = *(const short8v*)(xr + 320 + sq * 16 + 8);
    px  = *(const short4v*)(xr + (h << 5) + (ph << 4) + sq * 4);
    if (tid < 64) dtraw = zx[(base_b + tid) * DPROJ + 640 + h];
  }
  for (int c = 0; c < 16; ++c) {
    const int l0 = c << 6;
    // ---- phase 1: populate LDS from prefetched regs + dt scan ----
    *(short8v*)(pB + srow * 128 + ((sq * 32) ^ xs))      = pb0;
    *(short8v*)(pB + srow * 128 + ((sq * 32 + 16) ^ xs)) = pb1;
    *(short8v*)(pC + srow * 128 + ((sq * 32) ^ xs))      = pc0;
    *(short8v*)(pC + srow * 128 + ((sq * 32 + 16) ^ xs)) = pc1;
#pragma unroll
    for (int j = 0; j < 4; ++j) {
      const int p = sq * 4 + j;
      *(ushort_t*)(pX + p * 256 + ((srow * 2) ^ ((p & 7) << 4))) = (ushort_t)px[j];
    }
#pragma unroll
    for (int r = 0; r < 4; ++r) {
      const int p = lgp * 4 + r, n = (w << 4) + lr;
      *(ushort_t*)(pX + p * 256 + ((128 + n * 2) ^ ((p & 7) << 4))) = f2bf(hfrag[r]);
    }
    if (tid < 64) {
      float raw = dtraw + dtb_h;
      float dt = raw > 20.f ? raw : log1pf(expf(raw));
      float cum = dt * nA;
      for (int off = 1; off < 64; off <<= 1) {
        float v = __shfl_up(cum, off, 64);
        if (tid >= off) cum += v;
      }
      sdt[tid] = dt; slc[tid] = cum;
    }
    __syncthreads();
    // ---- phase 2: scaled B^T transpose + Pt*C + G GEMM ----
    const float lcT = slc[63];
    {
      const float coef = sdt[srow] * __expf(fminf(lcT - slc[srow], 0.f));
#pragma unroll
      for (int j = 0; j < 16; ++j) {
        const int n = sq * 16 + j;
        float bvf = bf2f((ushort_t)(j < 8 ? pb0[j] : pb1[j - 8]));
        *(ushort_t*)(pT + n * 128 + ((srow * 2) ^ ((n & 7) << 4))) = f2bf(coef * bvf);
      }
      const float Pt = __expf(slc[srow]);
      short8v q0, q1;
#pragma unroll
      for (int j = 0; j < 8; ++j) {
        q0[j] = (short)f2bf(Pt * bf2f((ushort_t)pc0[j]));
        q1[j] = (short)f2bf(Pt * bf2f((ushort_t)pc1[j]));
      }
      *(short8v*)(pA + srow * 256 + ((128 + sq * 32) ^ xs))      = q0;
      *(short8v*)(pA + srow * 256 + ((128 + sq * 32 + 16) ^ xs)) = q1;
    }
    f32x4 accg[4];
#pragma unroll
    for (int nt = 0; nt < 4; ++nt) accg[nt] = (f32x4){0.f, 0.f, 0.f, 0.f};
    {
      short8v a0 = *(const short8v*)(pC + ((w << 4) + lr) * 128 + ((lgp * 16) ^ xsl));
      short8v a1 = *(const short8v*)(pC + ((w << 4) + lr) * 128 + ((64 + lgp * 16) ^ xsl));
#pragma unroll
      for (int nt = 0; nt < 4; ++nt) {
        short8v b0 = *(const short8v*)(pB + (nt * 16 + lr) * 128 + ((lgp * 16) ^ xsl));
        short8v b1 = *(const short8v*)(pB + (nt * 16 + lr) * 128 + ((64 + lgp * 16) ^ xsl));
        accg[nt] = __builtin_amdgcn_mfma_f32_16x16x32_bf16(a0, b0, accg[nt], 0, 0, 0);
        accg[nt] = __builtin_amdgcn_mfma_f32_16x16x32_bf16(a1, b1, accg[nt], 0, 0, 0);
      }
    }
    __syncthreads();
    // ---- phase 3: chunk-state MFMA + h update + W write ----
    {
      short8v xa0 = *(const short8v*)(pX + lr * 256 + ((lgp * 16) ^ xsl));
      short8v xa1 = *(const short8v*)(pX + lr * 256 + ((64 + lgp * 16) ^ xsl));
      short8v bt0 = *(const short8v*)(pT + ((w << 4) + lr) * 128 + ((lgp * 16) ^ xsl));
      short8v bt1 = *(const short8v*)(pT + ((w << 4) + lr) * 128 + ((64 + lgp * 16) ^ xsl));
      f32x4 S = (f32x4){0.f, 0.f, 0.f, 0.f};
      S = __builtin_amdgcn_mfma_f32_16x16x32_bf16(xa0, bt0, S, 0, 0, 0);
      S = __builtin_amdgcn_mfma_f32_16x16x32_bf16(xa1, bt1, S, 0, 0, 0);
      const float Ac = __expf(lcT);
#pragma unroll
      for (int r = 0; r < 4; ++r) hfrag[r] = Ac * hfrag[r] + S[r];
    }
    {
      float lct_r[4];
#pragma unroll
      for (int r = 0; r < 4; ++r) lct_r[r] = slc[(w << 4) + lgp * 4 + r];
#pragma unroll
      for (int nt = 0; nt < 4; ++nt) {
        const int s = nt * 16 + lr;
        const float ds = sdt[s], ls = slc[s];
#pragma unroll
        for (int r = 0; r < 4; ++r) {
          const int t = (w << 4) + lgp * 4 + r;
          float wv = 0.f;
          if (s <= t) wv = ds * __expf(fminf(lct_r[r] - ls, 0.f)) * accg[nt][r];
          *(ushort_t*)(pA + t * 256 + ((s * 2) ^ ((t & 7) << 4))) = f2bf(wv);
        }
      }
    }
    __syncthreads();
    // ---- phase 4: next-chunk prefetch + Y GEMM + epilogue ----
    if (c < 15) {
      const ushort_t* xr = xcb + (base_b + l0 + 64 + srow) * CDIM;
      pb0 = *(const short8v*)(xr + 256 + sq * 16);
      pb1 = *(const short8v*)(xr + 256 + sq * 16 + 8);
      pc0 = *(const short8v*)(xr + 320 + sq * 16);
      pc1 = *(const short8v*)(xr + 320 + sq * 16 + 8);
      px  = *(const short4v*)(xr + (h << 5) + (ph << 4) + sq * 4);
      if (tid < 64) dtraw = zx[(base_b + l0 + 64 + tid) * DPROJ + 640 + h];
    }
    f32x4 accy = (f32x4){0.f, 0.f, 0.f, 0.f};
#pragma unroll
    for (int ks = 0; ks < 4; ++ks) {
      short8v aw = *(const short8v*)(pA + ((w << 4) + lr) * 256 + ((ks * 64 + lgp * 16) ^ xsl));
      short8v bx = *(const short8v*)(pX + lr * 256 + ((ks * 64 + lgp * 16) ^ xsl));
      accy = __builtin_amdgcn_mfma_f32_16x16x32_bf16(aw, bx, accy, 0, 0, 0);
    }
#pragma unroll
    for (int r = 0; r < 4; ++r) {
      const int t = (w << 4) + lgp * 4 + r;
      float xv = bf2f(*(const ushort_t*)(pX + lr * 256 + ((t * 2) ^ xsl)));
      ys[(base_b + l0 + t) * DI + (h << 5) + (ph << 4) + lr] = f2bf(accy[r] + dsk * xv);
    }
    __syncthreads();
  }
}

// ---------------- gate*silu(z), RMSNorm, out_proj (MFMA), residual add ----------------
__global__ __launch_bounds__(256) void k_gateout(const float* __restrict__ zx,
    const ushort_t* __restrict__ ysb, const ushort_t* __restrict__ owb,
    float* __restrict__ tok){
  __shared__ ushort_t Al[64 * 256];
  __shared__ ushort_t Bl[128 * 64];
  const int m0 = blockIdx.x * 64;
  const int tid = threadIdx.x;
  char* Ab = (char*)Al; char* Bb = (char*)Bl;
  {
    const int r = tid >> 2, t4 = tid & 3;
    const size_t row = (size_t)(m0 + r);
    const ushort_t* yp = ysb + row * 256 + t4 * 64;
    const float* zp = zx + row * DPROJ + t4 * 64;
    float p[64];
    float sq = 0.f;
#pragma unroll
    for (int k = 0; k < 8; ++k) {
      short8v y8 = *(const short8v*)(yp + 8 * k);
      float4 fz0 = *(const float4*)(zp + 8 * k);
      float4 fz1 = *(const float4*)(zp + 8 * k + 4);
      float zz[8] = {fz0.x, fz0.y, fz0.z, fz0.w, fz1.x, fz1.y, fz1.z, fz1.w};
#pragma unroll
      for (int j = 0; j < 8; ++j) {
        float a = bf2f((ushort_t)y8[j]) * (zz[j] / (1.f + __expf(-zz[j])));
        p[8 * k + j] = a; sq += a * a;
      }
    }
    sq += __shfl_xor(sq, 1, 4); sq += __shfl_xor(sq, 2, 4);
    float rstd = rsqrtf(sq * (1.f / 256.f) + EPS);
#pragma unroll
    for (int k = 0; k < 8; ++k) {
      short8v o;
#pragma unroll
      for (int e = 0; e < 8; ++e) o[e] = (short)f2bf(p[8*k + e] * rstd);
      *(short8v*)(Ab + r * 512 + ((t4 * 128 + 16 * k) ^ ((r & 7) << 4))) = o;
    }
  }
  const int w = tid >> 6, l = tid & 63, lr = l & 15, lgp = l >> 4;
  f32x4 acc[8];
#pragma unroll
  for (int nt = 0; nt < 8; ++nt) acc[nt] = (f32x4){0.f, 0.f, 0.f, 0.f};
  for (int kq = 0; kq < 4; ++kq) {
    __syncthreads();
    for (int idx = tid; idx < 128 * 8; idx += 256) {
      int row = idx >> 3, ch = idx & 7;
      short8v v = *(const short8v*)(owb + ((size_t)row << 8) + kq * 64 + (ch << 3));
      *(short8v*)(Bb + row * 128 + ((ch * 16) ^ ((row & 7) << 4))) = v;
    }
    __syncthreads();
    short8v a0 = *(const short8v*)(Ab + (16*w + lr) * 512 + ((kq * 128 +      lgp * 16) ^ ((lr & 7) << 4)));
    short8v a1 = *(const short8v*)(Ab + (16*w + lr) * 512 + ((kq * 128 + 64 + lgp * 16) ^ ((lr & 7) << 4)));
#pragma unroll
    for (int nt = 0; nt < 8; ++nt) {
      short8v b0 = *(const short8v*)(Bb + (nt * 16 + lr) * 128 + ((     lgp * 16) ^ ((lr & 7) << 4)));
      short8v b1 = *(const short8v*)(Bb + (nt * 16 + lr) * 128 + ((64 + lgp * 16) ^ ((lr & 7) << 4)));
      acc[nt] = __builtin_amdgcn_mfma_f32_16x16x32_bf16(a0, b0, acc[nt], 0, 0, 0);
      acc[nt] = __builtin_amdgcn_mfma_f32_16x16x32_bf16(a1, b1, acc[nt], 0, 0, 0);
    }
  }
#pragma unroll
  for (int nt = 0; nt < 8; ++nt) {
#pragma unroll
    for (int r = 0; r < 4; ++r) {
      tok[((size_t)(m0 + 16 * w + lgp * 4 + r)) * 128 + nt * 16 + lr] += acc[nt][r];
    }
  }
}

// ---------------- final LN + attention scores (MFMA) ----------------
__global__ __launch_bounds__(256) void k_score(const float* __restrict__ tok,
    const float* __restrict__ fg, const float* __restrict__ fb,
    const ushort_t* __restrict__ w1b, const float* __restrict__ b1,
    const float* __restrict__ w2, const float* __restrict__ b2,
    float* __restrict__ tokF, float* __restrict__ sc){
  __shared__ ushort_t Al[64 * 128];
  __shared__ ushort_t Wl[64 * 128];
  __shared__ float sb1[64], sw2[64];
  const int m0 = blockIdx.x * 64;
  const int tid = threadIdx.x;
  char* Ab = (char*)Al; char* Wb = (char*)Wl;
  for (int idx = tid; idx < 64 * 16; idx += 256) {
    int row = idx >> 4, ch = idx & 15;
    short8v v = *(const short8v*)(w1b + (row << 7) + (ch << 3));
    *(short8v*)(Wb + row * 256 + ((ch * 16) ^ ((row & 7) << 4))) = v;
  }
  if (tid < 64) { sb1[tid] = b1[tid]; sw2[tid] = w2[tid]; }
  {
    const int r = tid >> 2, t4 = tid & 3;
    const float* src = tok + (((size_t)(m0 + r)) << 7) + t4 * 32;
    float v[32];
    float s = 0.f, sq = 0.f;
#pragma unroll
    for (int k = 0; k < 8; ++k) {
      float4 f = *(const float4*)(src + 4 * k);
      v[4*k] = f.x; v[4*k+1] = f.y; v[4*k+2] = f.z; v[4*k+3] = f.w;
      s += f.x + f.y + f.z + f.w;
      sq += f.x*f.x + f.y*f.y + f.z*f.z + f.w*f.w;
    }
    s  += __shfl_xor(s, 1, 4);  s  += __shfl_xor(s, 2, 4);
    sq += __shfl_xor(sq, 1, 4); sq += __shfl_xor(sq, 2, 4);
    float mean = s * (1.f / 128.f);
    float var  = sq * (1.f / 128.f) - mean * mean;
    float rstd = rsqrtf(var + EPS);
    float* tdst = tokF + (((size_t)(m0 + r)) << 7) + t4 * 32;
#pragma unroll
    for (int k = 0; k < 4; ++k) {
      float o8[8];
      float4 g0 = *(const float4*)(fg + t4 * 32 + 8 * k);
      float4 g1 = *(const float4*)(fg + t4 * 32 + 8 * k + 4);
      float4 e0 = *(const float4*)(fb + t4 * 32 + 8 * k);
      float4 e1 = *(const float4*)(fb + t4 * 32 + 8 * k + 4);
      o8[0] = (v[8*k+0]-mean)*rstd*g0.x + e0.x; o8[1] = (v[8*k+1]-mean)*rstd*g0.y + e0.y;
      o8[2] = (v[8*k+2]-mean)*rstd*g0.z + e0.z; o8[3] = (v[8*k+3]-mean)*rstd*g0.w + e0.w;
      o8[4] = (v[8*k+4]-mean)*rstd*g1.x + e1.x; o8[5] = (v[8*k+5]-mean)*rstd*g1.y + e1.y;
      o8[6] = (v[8*k+6]-mean)*rstd*g1.z + e1.z; o8[7] = (v[8*k+7]-mean)*rstd*g1.w + e1.w;
      *(float4*)(tdst + 8*k)     = make_float4(o8[0], o8[1], o8[2], o8[3]);
      *(float4*)(tdst + 8*k + 4) = make_float4(o8[4], o8[5], o8[6], o8[7]);
      short8v ov;
#pragma unroll
      for (int e = 0; e < 8; ++e) ov[e] = (short)f2bf(o8[e]);
      *(short8v*)(Ab + r * 256 + ((t4 * 64 + 16 * k) ^ ((r & 7) << 4))) = ov;
    }
  }
  __syncthreads();
  const int w = tid >> 6, l = tid & 63, lr = l & 15, lgp = l >> 4;
  const int xsl = (lr & 7) << 4;
  short8v a[4];
#pragma unroll
  for (int ks = 0; ks < 4; ++ks)
    a[ks] = *(const short8v*)(Ab + (16 * w + lr) * 256 + ((ks * 64 + lgp * 16) ^ xsl));
  float sacc[4] = {0.f, 0.f, 0.f, 0.f};
#pragma unroll
  for (int nt = 0; nt < 4; ++nt) {
    f32x4 acc = (f32x4){0.f, 0.f, 0.f, 0.f};
#pragma unroll
    for (int ks = 0; ks < 4; ++ks) {
      short8v bb = *(const short8v*)(Wb + (nt * 16 + lr) * 256 + ((ks * 64 + lgp * 16) ^ xsl));
      acc = __builtin_amdgcn_mfma_f32_16x16x32_bf16(a[ks], bb, acc, 0, 0, 0);
    }
    const float bias = sb1[nt * 16 + lr], wv = sw2[nt * 16 + lr];
#pragma unroll
    for (int r = 0; r < 4; ++r) sacc[r] += tanhf(acc[r] + bias) * wv;
  }
#pragma unroll
  for (int r = 0; r < 4; ++r) {
    for (int off = 1; off < 16; off <<= 1) sacc[r] += __shfl_xor(sacc[r], off, 16);
  }
  if (lr == 0) {
    const float bb2 = b2[0];
#pragma unroll
    for (int r = 0; r < 4; ++r) sc[m0 + 16 * w + lgp * 4 + r] = sacc[r] + bb2;
  }
}

// ---------------- softmax pool phase 1: per-segment partials ----------------
__global__ __launch_bounds__(256) void k_pool1(const float* __restrict__ tokF,
    const float* __restrict__ sc, float* __restrict__ pp){
  __shared__ float sw[128];
  __shared__ float sacc[128];
  __shared__ float sse[2];
  const int bs = blockIdx.x, b = bs >> 3, seg = bs & 7, tid = threadIdx.x;
  const int l0 = (b << 10) + (seg << 7);
  if (tid < 128) sw[tid] = __expf(sc[l0 + tid]);
  __syncthreads();
  const int d = tid & 127, g = tid >> 7;
  const float* tf = tokF + ((size_t)(l0 + (g << 6))) * 128 + d;
  float acc = 0.f;
#pragma unroll 4
  for (int i = 0; i < 64; ++i) acc += sw[(g << 6) + i] * tf[(size_t)i * 128];
  if (g == 0) sacc[d] = acc;
  float e = (tid < 128) ? sw[tid] : 0.f;
  for (int off = 32; off; off >>= 1) e += __shfl_xor(e, off);
  if ((tid & 63) == 0 && tid < 128) sse[tid >> 6] = e;
  __syncthreads();
  if (g == 1) pp[bs * 132 + d] = sacc[d] + acc;
  if (tid == 0) pp[bs * 132 + 128] = sse[0] + sse[1];
}

// ---------------- softmax pool phase 2: reduce + l2 normalize ----------------
__global__ __launch_bounds__(128) void k_pool2(const float* __restrict__ pp,
    float* __restrict__ out){
  __shared__ float s2[2];
  const int b = blockIdx.x, tid = threadIdx.x;
  float num = 0.f, den = 0.f;
#pragma unroll
  for (int seg = 0; seg < 8; ++seg) {
    num += pp[(b * 8 + seg) * 132 + tid];
    den += pp[(b * 8 + seg) * 132 + 128];
  }
  float pooled = num / den;
  float sq = pooled * pooled;
  for (int off = 32; off; off >>= 1) sq += __shfl_xor(sq, off);
  if ((tid & 63) == 0) s2[tid >> 6] = sq;
  __syncthreads();
  float nrm = fmaxf(sqrtf(s2[0] + s2[1]), 1e-12f);
  out[(size_t)b * 128 + tid] = pooled / nrm;
}

extern "C" void kernel_launch(void* const* d_in, const int* in_sizes, int n_in,
                              void* d_out, int out_size, void* d_ws, size_t ws_size,
                              hipStream_t stream) {
  const float* x       = (const float*)d_in[0];
  const float* patch_w = (const float*)d_in[1];
  const float* patch_b = (const float*)d_in[2];
  const float* pe_g    = (const float*)d_in[3];
  const float* pe_b    = (const float*)d_in[4];
  const float* in_w    = (const float*)d_in[5];
  const float* conv_w  = (const float*)d_in[6];
  const float* conv_b  = (const float*)d_in[7];
  const float* dt_bias = (const float*)d_in[8];
  const float* A_log   = (const float*)d_in[9];
  const float* D_skip  = (const float*)d_in[10];
  const float* nw      = (const float*)d_in[11];
  const float* out_w   = (const float*)d_in[12];
  const float* ln_g    = (const float*)d_in[13];
  const float* ln_b    = (const float*)d_in[14];
  const float* fn_g    = (const float*)d_in[15];
  const float* fn_b    = (const float*)d_in[16];
  const float* w1      = (const float*)d_in[17];
  const float* b1      = (const float*)d_in[18];
  const float* w2      = (const float*)d_in[19];
  const float* b2      = (const float*)d_in[20];
  float* out = (float*)d_out;
  char* ws = (char*)d_ws;

  size_t off = 0;
  float* tok  = (float*)(ws + off); off += (size_t)NB * L * DM * 4;        //  8 MB
  float* zx   = (float*)(ws + off); off += (size_t)NB * L * DPROJ * 4;     // 40.5 MB
  ushort_t* xcb = (ushort_t*)(ws + off); off += (size_t)NB * L * CDIM * 2; // 12 MB
  ushort_t* ysb = (ushort_t*)(ws + off); off += (size_t)NB * L * DI * 2;   //  8 MB
  ushort_t* inwb = (ushort_t*)(ws + off); off += (size_t)4 * EPAD * 128 * 2;
  ushort_t* owb  = (ushort_t*)(ws + off); off += (size_t)4 * 128 * 256 * 2;
  ushort_t* pwb  = (ushort_t*)(ws + off); off += (size_t)128 * 768 * 2;
  float* biasin  = (float*)(ws + off); off += (size_t)4 * EPAD * 4;
  ushort_t* w1b  = (ushort_t*)(ws + off); off += (size_t)64 * 128 * 2;
  float* pp      = (float*)(ws + off); off += (size_t)128 * 132 * 4;
  float* tokF = zx;                                            // zx dead after layers
  float* scb  = (float*)(ws + (size_t)30 * 1024 * 1024);       // inside zx, past tokF

  {
    const int total = 4 * EPAD * 128 + 4 * 128 * 256 + 128 * 768 + 4 * EPAD + 64 * 128;
    k_cvt<<<(total + 255) / 256, 256, 0, stream>>>(in_w, ln_g, ln_b, out_w, nw, patch_w, w1,
                                                   inwb, owb, pwb, biasin, w1b);
  }
  k_patch<<<256, 256, 0, stream>>>(x, pwb, patch_b, pe_g, pe_b, tok);
  for (int ly = 0; ly < 4; ++ly) {
    k_inproj<<<512, 256, 0, stream>>>(tok, inwb + (size_t)ly * EPAD * 128,
                                      biasin + ly * EPAD, zx);
    k_conv<<<NB * 16 * 2, 256, 0, stream>>>(zx, conv_w + (size_t)ly * CDIM * 4,
                                            conv_b + ly * CDIM, xcb);
    k_ssd<<<NB * NH * 2, 256, 0, stream>>>(xcb, zx, dt_bias + ly * NH,
                                           A_log + ly * NH, D_skip + ly * NH, ysb);
    k_gateout<<<256, 256, 0, stream>>>(zx, ysb, owb + (size_t)ly * 128 * 256, tok);
  }
  k_score<<<256, 256, 0, stream>>>(tok, fn_g, fn_b, w1b, b1, w2, b2, tokF, scb);
  k_pool1<<<128, 256, 0, stream>>>(tokF, scb, pp);
  k_pool2<<<16, 128, 0, stream>>>(pp, out);
}

// Round 7
// 478.484 us; speedup vs baseline: 1.1663x; 1.1663x over previous
//
#include <hip/hip_runtime.h>
#include <math.h>

#define EPS 1e-5f

constexpr int NB      = 16;
constexpr int L       = 1024;
constexpr int DM      = 128;
constexpr int DI      = 256;
constexpr int DS      = 64;
constexpr int NH      = 8;
constexpr int DPROJ   = 648;   // 2*DI + 2*DS + NH
constexpr int CDIM    = 384;   // DI + 2*DS
constexpr int EPAD    = 656;   // DPROJ padded to 41*16

typedef __attribute__((ext_vector_type(8))) short short8v;
typedef __attribute__((ext_vector_type(4))) short short4v;
typedef __attribute__((ext_vector_type(4))) float f32x4;
typedef unsigned short ushort_t;

__device__ __forceinline__ float silu_f(float x){ return x / (1.f + expf(-x)); }
__device__ __forceinline__ ushort_t f2bf(float f){
  union { float f; unsigned int u; } v; v.f = f;
  unsigned int r = v.u + 0x7FFF + ((v.u >> 16) & 1);
  return (ushort_t)(r >> 16);
}
__device__ __forceinline__ float bf2f(ushort_t u){
  union { float f; unsigned int u; } v; v.u = ((unsigned int)u) << 16;
  return v.f;
}
__device__ __forceinline__ short8v pack8(float4 a, float4 b){
  short8v v;
  v[0]=(short)f2bf(a.x); v[1]=(short)f2bf(a.y); v[2]=(short)f2bf(a.z); v[3]=(short)f2bf(a.w);
  v[4]=(short)f2bf(b.x); v[5]=(short)f2bf(b.y); v[6]=(short)f2bf(b.z); v[7]=(short)f2bf(b.w);
  return v;
}

// ---------------- weight conversion / folding (runs once per launch) ----------------
__global__ __launch_bounds__(256) void k_cvt(const float* __restrict__ in_w,
    const float* __restrict__ ln_g, const float* __restrict__ ln_b,
    const float* __restrict__ out_w, const float* __restrict__ nw,
    const float* __restrict__ patch_w, const float* __restrict__ w1,
    ushort_t* __restrict__ inwb, ushort_t* __restrict__ owb,
    ushort_t* __restrict__ pwb, float* __restrict__ biasin,
    ushort_t* __restrict__ w1b){
  const int R1 = 4 * EPAD * 128, R2 = 4 * 128 * 256, R3 = 128 * 768, R4 = 4 * EPAD, R5 = 64 * 128;
  int i = blockIdx.x * 256 + threadIdx.x;
  if (i < R1) {
    int ly = i / (EPAD * 128), rem = i % (EPAD * 128), e = rem >> 7, d = rem & 127;
    float v = 0.f;
    if (e < DPROJ) v = in_w[((size_t)ly * DPROJ + e) * 128 + d] * ln_g[ly * 128 + d];
    inwb[i] = f2bf(v);
    return;
  }
  i -= R1;
  if (i < R2) {
    int ly = i >> 15, rem = i & 32767, e = rem & 255;
    owb[i] = f2bf(out_w[i] * nw[ly * 256 + e]);
    return;
  }
  i -= R2;
  if (i < R3) { pwb[i] = f2bf(patch_w[i]); return; }
  i -= R3;
  if (i < R4) {
    int ly = i / EPAD, e = i % EPAD;
    float s = 0.f;
    if (e < DPROJ) {
      const float* r = in_w + ((size_t)ly * DPROJ + e) * 128;
      const float* b = ln_b + ly * 128;
      for (int d = 0; d < 128; ++d) s += r[d] * b[d];
    }
    biasin[i] = s;
    return;
  }
  i -= R4;
  if (i < R5) w1b[i] = f2bf(w1[i]);
}

// ---------------- patch embed (MFMA) + pos layernorm ----------------
__global__ __launch_bounds__(256) void k_patch(const float* __restrict__ x,
    const ushort_t* __restrict__ pwb, const float* __restrict__ pb,
    const float* __restrict__ pg, const float* __restrict__ pbe,
    float* __restrict__ tok){
  __shared__ ushort_t Al[64 * 128];
  __shared__ ushort_t Bl[128 * 128];
  __shared__ float spb[128], spg[128], spe[128];
  const int m0 = blockIdx.x * 64;
  const int tid = threadIdx.x;
  char* Ab = (char*)Al; char* Bb = (char*)Bl;
  if (tid < 128) { spb[tid] = pb[tid]; spg[tid] = pg[tid]; spe[tid] = pbe[tid]; }
  const int w = tid >> 6, l = tid & 63, lr = l & 15, lgp = l >> 4;
  f32x4 acc[8];
#pragma unroll
  for (int nt = 0; nt < 8; ++nt) acc[nt] = (f32x4){0.f, 0.f, 0.f, 0.f};
  for (int kc = 0; kc < 6; ++kc) {
    __syncthreads();
    for (int idx = tid; idx < 128 * 16; idx += 256) {
      int n = idx >> 4, ch = idx & 15;
      short8v v = *(const short8v*)(pwb + (size_t)n * 768 + kc * 128 + (ch << 3));
      *(short8v*)(Bb + n * 256 + ((ch * 16) ^ ((n & 7) << 4))) = v;
    }
    {
      const int c = kc >> 1;
      for (int i = tid; i < 1024; i += 256) {
        int t = i >> 4, p = (i >> 1) & 7, o = i & 1;
        int T = m0 + t, bb = T >> 10, tl = T & 1023, hp = tl >> 5, wp = tl & 31;
        const float* src = x + (((size_t)(bb * 3 + c) * 512 + hp * 16 + ((kc & 1) << 3) + p) * 512
                                + wp * 16 + o * 8);
        float4 f0 = *(const float4*)src;
        float4 f1 = *(const float4*)(src + 4);
        short8v v = pack8(f0, f1);
        int kk = p * 16 + o * 8;
        *(short8v*)(Ab + t * 256 + ((kk * 2) ^ ((t & 7) << 4))) = v;
      }
    }
    __syncthreads();
    short8v a[4];
#pragma unroll
    for (int ks = 0; ks < 4; ++ks)
      a[ks] = *(const short8v*)(Ab + (16 * w + lr) * 256 + ((ks * 64 + lgp * 16) ^ ((lr & 7) << 4)));
#pragma unroll
    for (int nt = 0; nt < 8; ++nt) {
#pragma unroll
      for (int ks = 0; ks < 4; ++ks) {
        short8v b = *(const short8v*)(Bb + (nt * 16 + lr) * 256 + ((ks * 64 + lgp * 16) ^ ((lr & 7) << 4)));
        acc[nt] = __builtin_amdgcn_mfma_f32_16x16x32_bf16(a[ks], b, acc[nt], 0, 0, 0);
      }
    }
  }
  float s4[4] = {0,0,0,0}, q4[4] = {0,0,0,0};
#pragma unroll
  for (int nt = 0; nt < 8; ++nt) {
    const float bb = spb[nt * 16 + lr];
#pragma unroll
    for (int r = 0; r < 4; ++r) { float v = acc[nt][r] + bb; s4[r] += v; q4[r] += v * v; }
  }
#pragma unroll
  for (int r = 0; r < 4; ++r) {
    for (int off = 1; off < 16; off <<= 1) {
      s4[r] += __shfl_xor(s4[r], off, 16);
      q4[r] += __shfl_xor(q4[r], off, 16);
    }
  }
#pragma unroll
  for (int r = 0; r < 4; ++r) {
    float mean = s4[r] * (1.f / 128.f);
    float var  = q4[r] * (1.f / 128.f) - mean * mean;
    float rstd = rsqrtf(var + EPS);
    const size_t row = (size_t)(m0 + 16 * w + lgp * 4 + r) * 128;
#pragma unroll
    for (int nt = 0; nt < 8; ++nt) {
      int col = nt * 16 + lr;
      float v = acc[nt][r] + spb[col];
      tok[row + col] = (v - mean) * rstd * spg[col] + spe[col];
    }
  }
}

// ---------------- fused layernorm + in_proj (MFMA, M=128 tile) ----------------
__global__ __launch_bounds__(256) void k_inproj(const float* __restrict__ tok,
    const ushort_t* __restrict__ inwb, const float* __restrict__ biasin,
    float* __restrict__ zx){
  __shared__ ushort_t Al[128 * 128];
  __shared__ ushort_t Bl[176 * 128];
  __shared__ float sBias[176];
  const int blk = blockIdx.x;
  const int mb = blk >> 2, nb = blk & 3;
  const int m0 = mb << 7, n0 = nb * 176;
  const int NT = (nb == 3) ? 128 : 176;
  const int tid = threadIdx.x;
  char* Ab = (char*)Al; char* Bb = (char*)Bl;
  for (int idx = tid; idx < (NT << 4); idx += 256) {
    int row = idx >> 4, ch = idx & 15;
    short8v v = *(const short8v*)(inwb + ((size_t)(n0 + row) << 7) + (ch << 3));
    *(short8v*)(Bb + row * 256 + ((ch * 16) ^ ((row & 7) << 4))) = v;
  }
  for (int idx = tid; idx < NT; idx += 256) sBias[idx] = biasin[n0 + idx];
  for (int rp = 0; rp < 2; ++rp) {
    const int r = (rp << 6) + (tid >> 2), t4 = tid & 3;
    const float* src = tok + (((size_t)(m0 + r)) << 7) + t4 * 32;
    float v[32];
    float s = 0.f, sq = 0.f;
#pragma unroll
    for (int k = 0; k < 8; ++k) {
      float4 f = *(const float4*)(src + 4 * k);
      v[4*k] = f.x; v[4*k+1] = f.y; v[4*k+2] = f.z; v[4*k+3] = f.w;
      s += f.x + f.y + f.z + f.w;
      sq += f.x*f.x + f.y*f.y + f.z*f.z + f.w*f.w;
    }
    s  += __shfl_xor(s, 1, 4);  s  += __shfl_xor(s, 2, 4);
    sq += __shfl_xor(sq, 1, 4); sq += __shfl_xor(sq, 2, 4);
    float mean = s * (1.f / 128.f);
    float var  = sq * (1.f / 128.f) - mean * mean;
    float rstd = rsqrtf(var + EPS);
#pragma unroll
    for (int k = 0; k < 4; ++k) {
      short8v o;
#pragma unroll
      for (int e = 0; e < 8; ++e) o[e] = (short)f2bf((v[8*k + e] - mean) * rstd);
      *(short8v*)(Ab + r * 256 + ((t4 * 64 + 16 * k) ^ ((r & 7) << 4))) = o;
    }
  }
  __syncthreads();
  const int w = tid >> 6, l = tid & 63, lr = l & 15, lgp = l >> 4;
  const int xsl = (lr & 7) << 4;
  short8v a[2][4];
#pragma unroll
  for (int mi = 0; mi < 2; ++mi) {
    const int mt = w + mi * 4;
#pragma unroll
    for (int ks = 0; ks < 4; ++ks)
      a[mi][ks] = *(const short8v*)(Ab + (16 * mt + lr) * 256 + ((ks * 64 + lgp * 16) ^ xsl));
  }
  const int NTT = NT >> 4;
  for (int nt = 0; nt < NTT; ++nt) {
    f32x4 acc0 = (f32x4){0.f, 0.f, 0.f, 0.f};
    f32x4 acc1 = (f32x4){0.f, 0.f, 0.f, 0.f};
#pragma unroll
    for (int ks = 0; ks < 4; ++ks) {
      short8v b = *(const short8v*)(Bb + (nt * 16 + lr) * 256 + ((ks * 64 + lgp * 16) ^ xsl));
      acc0 = __builtin_amdgcn_mfma_f32_16x16x32_bf16(a[0][ks], b, acc0, 0, 0, 0);
      acc1 = __builtin_amdgcn_mfma_f32_16x16x32_bf16(a[1][ks], b, acc1, 0, 0, 0);
    }
    const int col = n0 + nt * 16 + lr;
    if (col < DPROJ) {
      const float bias = sBias[nt * 16 + lr];
#pragma unroll
      for (int r = 0; r < 4; ++r) {
        zx[((size_t)(m0 + 16 * w       + lgp * 4 + r)) * DPROJ + col] = acc0[r] + bias;
        zx[((size_t)(m0 + 16 * (w + 4) + lgp * 4 + r)) * DPROJ + col] = acc1[r] + bias;
      }
    }
  }
}

// ---------------- causal depthwise conv + silu (bf16 out) + fused dt cumsum ----------------
// grid NB*16*2; cg==0 blocks additionally compute dt/lcb/Acb for their 64-token chunk
constexpr int CONVC = 192;
__global__ __launch_bounds__(256) void k_conv(const float* __restrict__ zx,
    const float* __restrict__ cw, const float* __restrict__ cb,
    const float* __restrict__ dtbias, const float* __restrict__ Alog,
    ushort_t* __restrict__ xc, float* __restrict__ dtb,
    float* __restrict__ lcb, float* __restrict__ Acb){
  __shared__ float st[67][CONVC];
  __shared__ float swt[CONVC][4];
  __shared__ float sbias[CONVC];
  const int blk = blockIdx.x;
  const int cg = blk & 1, tile = (blk >> 1) & 15, b = blk >> 5;
  const int l0 = tile << 6, ch0 = cg * CONVC;
  const int tid = threadIdx.x;
  for (int i = tid; i < CONVC; i += 256) {
    float4 wv = *(const float4*)(cw + (size_t)(ch0 + i) * 4);
    swt[i][0] = wv.x; swt[i][1] = wv.y; swt[i][2] = wv.z; swt[i][3] = wv.w;
    sbias[i] = cb[ch0 + i];
  }
  for (int i = tid; i < 67 * 48; i += 256) {
    int rr = i / 48, q4 = i % 48;
    int lrow = l0 + rr - 3;
    float4 v = make_float4(0.f, 0.f, 0.f, 0.f);
    if (lrow >= 0) v = *(const float4*)(zx + ((size_t)(b << 10) + lrow) * DPROJ + DI + ch0 + q4 * 4);
    *(float4*)(&st[rr][q4 * 4]) = v;
  }
  // fused dt: 4 waves x 2 heads each, lanes = tokens of this chunk
  if (cg == 0) {
    const int wv = tid >> 6, lane = tid & 63;
#pragma unroll
    for (int i = 0; i < 2; ++i) {
      const int hh = wv * 2 + i;
      float raw = zx[((size_t)(b << 10) + l0 + lane) * DPROJ + 640 + hh] + dtbias[hh];
      float dt = raw > 20.f ? raw : log1pf(expf(raw));
      float cum = dt * (-expf(Alog[hh]));
      for (int off = 1; off < 64; off <<= 1) {
        float v = __shfl_up(cum, off, 64);
        if (lane >= off) cum += v;
      }
      size_t o = ((size_t)((b << 3) + hh) << 10) + l0 + lane;
      dtb[o] = dt; lcb[o] = cum;
      if (lane == 63) Acb[((b << 3) + hh) * 16 + tile] = expf(cum);
    }
  }
  __syncthreads();
  for (int i = tid; i < 64 * 48; i += 256) {
    int t = i / 48, g = i % 48;
    short4v ov;
#pragma unroll
    for (int j = 0; j < 4; ++j) {
      int c2 = g * 4 + j;
      float acc = sbias[c2] + st[t][c2] * swt[c2][0] + st[t+1][c2] * swt[c2][1]
                + st[t+2][c2] * swt[c2][2] + st[t+3][c2] * swt[c2][3];
      ov[j] = (short)f2bf(silu_f(acc));
    }
    *(short4v*)(xc + ((size_t)(b << 10) + l0 + t) * CDIM + ch0 + g * 4) = ov;
  }
}

// ---------------- SSD step 2: per-chunk state S_c (MFMA, bf16 in) ----------------
// grid NB*NH*16 = 2048, 256 threads
__global__ __launch_bounds__(256) void k_cstate(const ushort_t* __restrict__ xc,
    const float* __restrict__ dtb, const float* __restrict__ lcb,
    float* __restrict__ Sc){
  __shared__ ushort_t sXc[32 * 64];   // A_op [p][s]
  __shared__ ushort_t sBt[64 * 64];   // B_op [n][s]
  __shared__ float scoef[64];
  const int blk = blockIdx.x;
  const int c = blk & 15, h = (blk >> 4) & 7, b = blk >> 7;
  const int tid = threadIdx.x;
  const int l0 = c << 6;
  char* pA = (char*)sXc; char* pB = (char*)sBt;
  const size_t obh = ((size_t)((b << 3) + h) << 10) + l0;
  if (tid < 64) {
    float lcT = lcb[obh + 63];
    scoef[tid] = dtb[obh + tid] * __expf(fminf(lcT - lcb[obh + tid], 0.f));
  }
  const int s = tid >> 2, q = tid & 3;
  const ushort_t* xr = xc + ((size_t)(b << 10) + l0 + s) * CDIM;
  short8v b0 = *(const short8v*)(xr + 256 + q * 16);
  short8v b1 = *(const short8v*)(xr + 256 + q * 16 + 8);
  short8v x8 = *(const short8v*)(xr + (h << 5) + q * 8);
#pragma unroll
  for (int j = 0; j < 16; ++j) {
    const int n = q * 16 + j;
    ushort_t bv = (ushort_t)(j < 8 ? b0[j] : b1[j - 8]);
    *(ushort_t*)(pB + n * 128 + ((s * 2) ^ ((n & 7) << 4))) = bv;
  }
  __syncthreads();
  const float cf = scoef[s];
#pragma unroll
  for (int j = 0; j < 8; ++j) {
    const int p = q * 8 + j;
    *(ushort_t*)(pA + p * 128 + ((s * 2) ^ ((p & 7) << 4))) = f2bf(cf * bf2f((ushort_t)x8[j]));
  }
  __syncthreads();
  const int w = tid >> 6, l = tid & 63, lr = l & 15, lgp = l >> 4;
  const int xsl = (lr & 7) << 4;
  const int pt = w & 1, ng = w >> 1;
  short8v a0 = *(const short8v*)(pA + (pt * 16 + lr) * 128 + ((lgp * 16) ^ xsl));
  short8v a1 = *(const short8v*)(pA + (pt * 16 + lr) * 128 + ((64 + lgp * 16) ^ xsl));
  float* dst = Sc + ((size_t)blk << 11);
#pragma unroll
  for (int ni = 0; ni < 2; ++ni) {
    const int nt = ng * 2 + ni;
    f32x4 acc = (f32x4){0.f, 0.f, 0.f, 0.f};
    short8v bb0 = *(const short8v*)(pB + (nt * 16 + lr) * 128 + ((lgp * 16) ^ xsl));
    short8v bb1 = *(const short8v*)(pB + (nt * 16 + lr) * 128 + ((64 + lgp * 16) ^ xsl));
    acc = __builtin_amdgcn_mfma_f32_16x16x32_bf16(a0, bb0, acc, 0, 0, 0);
    acc = __builtin_amdgcn_mfma_f32_16x16x32_bf16(a1, bb1, acc, 0, 0, 0);
#pragma unroll
    for (int r = 0; r < 4; ++r)
      dst[(pt * 16 + lgp * 4 + r) * 64 + nt * 16 + lr] = acc[r];
  }
}

// ---------------- SSD step 3: inter-chunk scan ----------------
__global__ __launch_bounds__(256) void k_hscan(float* __restrict__ Sc, const float* __restrict__ Acb){
  const int blk = blockIdx.x;
  const int bh = blk >> 3;
  const int e = ((blk & 7) << 8) + threadIdx.x;
  float hs = 0.f;
  const size_t base = ((size_t)bh << 15) + e;
  for (int c = 0; c < 16; ++c) {
    const size_t o = base + ((size_t)c << 11);
    float v = Sc[o];
    Sc[o] = hs;
    hs = Acb[(bh << 4) + c] * hs + v;
  }
}

// ---------------- SSD step 4: within-chunk outputs — full MFMA (bf16 in/out) ----------------
__global__ __launch_bounds__(256) void k_chunky(const ushort_t* __restrict__ xc,
    const float* __restrict__ h0buf, const float* __restrict__ dtb,
    const float* __restrict__ lcb, const float* __restrict__ Dsk,
    ushort_t* __restrict__ ys){
  __shared__ ushort_t sC[64 * 64];
  __shared__ ushort_t sBm[64 * 64];
  __shared__ ushort_t sAW[64 * 128];
  __shared__ ushort_t sBX[32 * 128];
  __shared__ float sXT[32][65];
  __shared__ float sdt[64], slc[64];
  const int blk = blockIdx.x;
  const int c = blk & 15, h = (blk >> 4) & 7, b = blk >> 7;
  const int tid = threadIdx.x;
  const int l0 = c << 6;
  char* pC = (char*)sC; char* pB = (char*)sBm; char* pA = (char*)sAW; char* pX = (char*)sBX;
  const size_t obh = ((size_t)((b << 3) + h) << 10) + l0;
  if (tid < 64) { sdt[tid] = dtb[obh + tid]; slc[tid] = lcb[obh + tid]; }
  {
    const int row = tid >> 2, q = tid & 3;
    const ushort_t* xr = xc + ((size_t)(b << 10) + l0 + row) * CDIM;
    const int xs = (row & 7) << 4;
    short8v b0 = *(const short8v*)(xr + 256 + q * 16);
    short8v b1 = *(const short8v*)(xr + 256 + q * 16 + 8);
    *(short8v*)(pB + row * 128 + ((q * 32) ^ xs))      = b0;
    *(short8v*)(pB + row * 128 + ((q * 32 + 16) ^ xs)) = b1;
    short8v c0 = *(const short8v*)(xr + 320 + q * 16);
    short8v c1 = *(const short8v*)(xr + 320 + q * 16 + 8);
    *(short8v*)(pC + row * 128 + ((q * 32) ^ xs))      = c0;
    *(short8v*)(pC + row * 128 + ((q * 32 + 16) ^ xs)) = c1;
    const float Pt = __expf(lcb[obh + row]);
    short8v q0, q1;
#pragma unroll
    for (int j = 0; j < 8; ++j) {
      q0[j] = (short)f2bf(Pt * bf2f((ushort_t)c0[j]));
      q1[j] = (short)f2bf(Pt * bf2f((ushort_t)c1[j]));
    }
    *(short8v*)(pA + row * 256 + ((128 + q * 32) ^ xs))      = q0;
    *(short8v*)(pA + row * 256 + ((128 + q * 32 + 16) ^ xs)) = q1;
    short8v x8 = *(const short8v*)(xr + (h << 5) + q * 8);
#pragma unroll
    for (int j = 0; j < 8; ++j) sXT[q * 8 + j][row] = bf2f((ushort_t)x8[j]);
  }
  {
    const int p = tid >> 3, n8 = (tid & 7) << 3;
    float4 h0a = *(const float4*)(h0buf + ((size_t)blk << 11) + (p << 6) + n8);
    float4 h0b = *(const float4*)(h0buf + ((size_t)blk << 11) + (p << 6) + n8 + 4);
    *(short8v*)(pX + p * 256 + (((64 + n8) * 2) ^ ((p & 7) << 4))) = pack8(h0a, h0b);
  }
  __syncthreads();
  {
    const int p = tid >> 3, s8 = (tid & 7) << 3;
    short8v vx;
#pragma unroll
    for (int e = 0; e < 8; ++e) vx[e] = (short)f2bf(sXT[p][s8 + e]);
    *(short8v*)(pX + p * 256 + ((s8 * 2) ^ ((p & 7) << 4))) = vx;
  }
  const int w = tid >> 6, l = tid & 63, lr = l & 15, lgp = l >> 4;
  const int xsl = (lr & 7) << 4;
  f32x4 accg[4];
#pragma unroll
  for (int nt = 0; nt < 4; ++nt) accg[nt] = (f32x4){0.f, 0.f, 0.f, 0.f};
  {
    short8v a0 = *(const short8v*)(pC + (16 * w + lr) * 128 + ((lgp * 16) ^ xsl));
    short8v a1 = *(const short8v*)(pC + (16 * w + lr) * 128 + ((64 + lgp * 16) ^ xsl));
#pragma unroll
    for (int nt = 0; nt < 4; ++nt) {
      short8v b0 = *(const short8v*)(pB + (nt * 16 + lr) * 128 + ((lgp * 16) ^ xsl));
      short8v b1 = *(const short8v*)(pB + (nt * 16 + lr) * 128 + ((64 + lgp * 16) ^ xsl));
      accg[nt] = __builtin_amdgcn_mfma_f32_16x16x32_bf16(a0, b0, accg[nt], 0, 0, 0);
      accg[nt] = __builtin_amdgcn_mfma_f32_16x16x32_bf16(a1, b1, accg[nt], 0, 0, 0);
    }
  }
#pragma unroll
  for (int nt = 0; nt < 4; ++nt) {
    const int s = nt * 16 + lr;
    const float ds = sdt[s], ls = slc[s];
#pragma unroll
    for (int r = 0; r < 4; ++r) {
      const int t = 16 * w + lgp * 4 + r;
      float wv = 0.f;
      if (s <= t) wv = ds * __expf(fminf(slc[t] - ls, 0.f)) * accg[nt][r];
      *(ushort_t*)(pA + t * 256 + ((s * 2) ^ ((t & 7) << 4))) = f2bf(wv);
    }
  }
  __syncthreads();
  f32x4 accy[2];
  accy[0] = (f32x4){0.f, 0.f, 0.f, 0.f};
  accy[1] = (f32x4){0.f, 0.f, 0.f, 0.f};
  short8v aw[4];
#pragma unroll
  for (int ks = 0; ks < 4; ++ks)
    aw[ks] = *(const short8v*)(pA + (16 * w + lr) * 256 + ((ks * 64 + lgp * 16) ^ xsl));
#pragma unroll
  for (int nt = 0; nt < 2; ++nt) {
#pragma unroll
    for (int ks = 0; ks < 4; ++ks) {
      short8v bx = *(const short8v*)(pX + (nt * 16 + lr) * 256 + ((ks * 64 + lgp * 16) ^ xsl));
      accy[nt] = __builtin_amdgcn_mfma_f32_16x16x32_bf16(aw[ks], bx, accy[nt], 0, 0, 0);
    }
  }
  const float dsk = Dsk[h];
#pragma unroll
  for (int nt = 0; nt < 2; ++nt) {
    const int p = nt * 16 + lr;
#pragma unroll
    for (int r = 0; r < 4; ++r) {
      const int t = 16 * w + lgp * 4 + r;
      ys[((size_t)(b << 10) + l0 + t) * DI + (h << 5) + p] = f2bf(accy[nt][r] + dsk * sXT[p][t]);
    }
  }
}

// ---------------- gate*silu(z), RMSNorm, out_proj (MFMA), residual add ----------------
__global__ __launch_bounds__(256) void k_gateout(const float* __restrict__ zx,
    const ushort_t* __restrict__ ysb, const ushort_t* __restrict__ owb,
    float* __restrict__ tok){
  __shared__ ushort_t Al[64 * 256];
  __shared__ ushort_t Bl[128 * 64];
  const int m0 = blockIdx.x * 64;
  const int tid = threadIdx.x;
  char* Ab = (char*)Al; char* Bb = (char*)Bl;
  {
    const int r = tid >> 2, t4 = tid & 3;
    const size_t row = (size_t)(m0 + r);
    const ushort_t* yp = ysb + row * 256 + t4 * 64;
    const float* zp = zx + row * DPROJ + t4 * 64;
    float p[64];
    float sq = 0.f;
#pragma unroll
    for (int k = 0; k < 8; ++k) {
      short8v y8 = *(const short8v*)(yp + 8 * k);
      float4 fz0 = *(const float4*)(zp + 8 * k);
      float4 fz1 = *(const float4*)(zp + 8 * k + 4);
      float zz[8] = {fz0.x, fz0.y, fz0.z, fz0.w, fz1.x, fz1.y, fz1.z, fz1.w};
#pragma unroll
      for (int j = 0; j < 8; ++j) {
        float a = bf2f((ushort_t)y8[j]) * (zz[j] / (1.f + __expf(-zz[j])));
        p[8 * k + j] = a; sq += a * a;
      }
    }
    sq += __shfl_xor(sq, 1, 4); sq += __shfl_xor(sq, 2, 4);
    float rstd = rsqrtf(sq * (1.f / 256.f) + EPS);
#pragma unroll
    for (int k = 0; k < 8; ++k) {
      short8v o;
#pragma unroll
      for (int e = 0; e < 8; ++e) o[e] = (short)f2bf(p[8*k + e] * rstd);
      *(short8v*)(Ab + r * 512 + ((t4 * 128 + 16 * k) ^ ((r & 7) << 4))) = o;
    }
  }
  const int w = tid >> 6, l = tid & 63, lr = l & 15, lgp = l >> 4;
  f32x4 acc[8];
#pragma unroll
  for (int nt = 0; nt < 8; ++nt) acc[nt] = (f32x4){0.f, 0.f, 0.f, 0.f};
  for (int kq = 0; kq < 4; ++kq) {
    __syncthreads();
    for (int idx = tid; idx < 128 * 8; idx += 256) {
      int row = idx >> 3, ch = idx & 7;
      short8v v = *(const short8v*)(owb + ((size_t)row << 8) + kq * 64 + (ch << 3));
      *(short8v*)(Bb + row * 128 + ((ch * 16) ^ ((row & 7) << 4))) = v;
    }
    __syncthreads();
    short8v a0 = *(const short8v*)(Ab + (16*w + lr) * 512 + ((kq * 128 +      lgp * 16) ^ ((lr & 7) << 4)));
    short8v a1 = *(const short8v*)(Ab + (16*w + lr) * 512 + ((kq * 128 + 64 + lgp * 16) ^ ((lr & 7) << 4)));
#pragma unroll
    for (int nt = 0; nt < 8; ++nt) {
      short8v b0 = *(const short8v*)(Bb + (nt * 16 + lr) * 128 + ((     lgp * 16) ^ ((lr & 7) << 4)));
      short8v b1 = *(const short8v*)(Bb + (nt * 16 + lr) * 128 + ((64 + lgp * 16) ^ ((lr & 7) << 4)));
      acc[nt] = __builtin_amdgcn_mfma_f32_16x16x32_bf16(a0, b0, acc[nt], 0, 0, 0);
      acc[nt] = __builtin_amdgcn_mfma_f32_16x16x32_bf16(a1, b1, acc[nt], 0, 0, 0);
    }
  }
#pragma unroll
  for (int nt = 0; nt < 8; ++nt) {
#pragma unroll
    for (int r = 0; r < 4; ++r) {
      tok[((size_t)(m0 + 16 * w + lgp * 4 + r)) * 128 + nt * 16 + lr] += acc[nt][r];
    }
  }
}

// ---------------- final LN + attention scores (MFMA) ----------------
__global__ __launch_bounds__(256) void k_score(const float* __restrict__ tok,
    const float* __restrict__ fg, const float* __restrict__ fb,
    const ushort_t* __restrict__ w1b, const float* __restrict__ b1,
    const float* __restrict__ w2, const float* __restrict__ b2,
    float* __restrict__ tokF, float* __restrict__ sc){
  __shared__ ushort_t Al[64 * 128];
  __shared__ ushort_t Wl[64 * 128];
  __shared__ float sb1[64], sw2[64];
  const int m0 = blockIdx.x * 64;
  const int tid = threadIdx.x;
  char* Ab = (char*)Al; char* Wb = (char*)Wl;
  for (int idx = tid; idx < 64 * 16; idx += 256) {
    int row = idx >> 4, ch = idx & 15;
    short8v v = *(const short8v*)(w1b + (row << 7) + (ch << 3));
    *(short8v*)(Wb + row * 256 + ((ch * 16) ^ ((row & 7) << 4))) = v;
  }
  if (tid < 64) { sb1[tid] = b1[tid]; sw2[tid] = w2[tid]; }
  {
    const int r = tid >> 2, t4 = tid & 3;
    const float* src = tok + (((size_t)(m0 + r)) << 7) + t4 * 32;
    float v[32];
    float s = 0.f, sq = 0.f;
#pragma unroll
    for (int k = 0; k < 8; ++k) {
      float4 f = *(const float4*)(src + 4 * k);
      v[4*k] = f.x; v[4*k+1] = f.y; v[4*k+2] = f.z; v[4*k+3] = f.w;
      s += f.x + f.y + f.z + f.w;
      sq += f.x*f.x + f.y*f.y + f.z*f.z + f.w*f.w;
    }
    s  += __shfl_xor(s, 1, 4);  s  += __shfl_xor(s, 2, 4);
    sq += __shfl_xor(sq, 1, 4); sq += __shfl_xor(sq, 2, 4);
    float mean = s * (1.f / 128.f);
    float var  = sq * (1.f / 128.f) - mean * mean;
    float rstd = rsqrtf(var + EPS);
    float* tdst = tokF + (((size_t)(m0 + r)) << 7) + t4 * 32;
#pragma unroll
    for (int k = 0; k < 4; ++k) {
      float o8[8];
      float4 g0 = *(const float4*)(fg + t4 * 32 + 8 * k);
      float4 g1 = *(const float4*)(fg + t4 * 32 + 8 * k + 4);
      float4 e0 = *(const float4*)(fb + t4 * 32 + 8 * k);
      float4 e1 = *(const float4*)(fb + t4 * 32 + 8 * k + 4);
      o8[0] = (v[8*k+0]-mean)*rstd*g0.x + e0.x; o8[1] = (v[8*k+1]-mean)*rstd*g0.y + e0.y;
      o8[2] = (v[8*k+2]-mean)*rstd*g0.z + e0.z; o8[3] = (v[8*k+3]-mean)*rstd*g0.w + e0.w;
      o8[4] = (v[8*k+4]-mean)*rstd*g1.x + e1.x; o8[5] = (v[8*k+5]-mean)*rstd*g1.y + e1.y;
      o8[6] = (v[8*k+6]-mean)*rstd*g1.z + e1.z; o8[7] = (v[8*k+7]-mean)*rstd*g1.w + e1.w;
      *(float4*)(tdst + 8*k)     = make_float4(o8[0], o8[1], o8[2], o8[3]);
      *(float4*)(tdst + 8*k + 4) = make_float4(o8[4], o8[5], o8[6], o8[7]);
      short8v ov;
#pragma unroll
      for (int e = 0; e < 8; ++e) ov[e] = (short)f2bf(o8[e]);
      *(short8v*)(Ab + r * 256 + ((t4 * 64 + 16 * k) ^ ((r & 7) << 4))) = ov;
    }
  }
  __syncthreads();
  const int w = tid >> 6, l = tid & 63, lr = l & 15, lgp = l >> 4;
  const int xsl = (lr & 7) << 4;
  short8v a[4];
#pragma unroll
  for (int ks = 0; ks < 4; ++ks)
    a[ks] = *(const short8v*)(Ab + (16 * w + lr) * 256 + ((ks * 64 + lgp * 16) ^ xsl));
  float sacc[4] = {0.f, 0.f, 0.f, 0.f};
#pragma unroll
  for (int nt = 0; nt < 4; ++nt) {
    f32x4 acc = (f32x4){0.f, 0.f, 0.f, 0.f};
#pragma unroll
    for (int ks = 0; ks < 4; ++ks) {
      short8v bb = *(const short8v*)(Wb + (nt * 16 + lr) * 256 + ((ks * 64 + lgp * 16) ^ xsl));
      acc = __builtin_amdgcn_mfma_f32_16x16x32_bf16(a[ks], bb, acc, 0, 0, 0);
    }
    const float bias = sb1[nt * 16 + lr], wv = sw2[nt * 16 + lr];
#pragma unroll
    for (int r = 0; r < 4; ++r) sacc[r] += tanhf(acc[r] + bias) * wv;
  }
#pragma unroll
  for (int r = 0; r < 4; ++r) {
    for (int off = 1; off < 16; off <<= 1) sacc[r] += __shfl_xor(sacc[r], off, 16);
  }
  if (lr == 0) {
    const float bb2 = b2[0];
#pragma unroll
    for (int r = 0; r < 4; ++r) sc[m0 + 16 * w + lgp * 4 + r] = sacc[r] + bb2;
  }
}

// ---------------- softmax pool phase 1: per-segment partials ----------------
__global__ __launch_bounds__(256) void k_pool1(const float* __restrict__ tokF,
    const float* __restrict__ sc, float* __restrict__ pp){
  __shared__ float sw[128];
  __shared__ float sacc[128];
  __shared__ float sse[2];
  const int bs = blockIdx.x, b = bs >> 3, seg = bs & 7, tid = threadIdx.x;
  const int l0 = (b << 10) + (seg << 7);
  if (tid < 128) sw[tid] = __expf(sc[l0 + tid]);
  __syncthreads();
  const int d = tid & 127, g = tid >> 7;
  const float* tf = tokF + ((size_t)(l0 + (g << 6))) * 128 + d;
  float acc = 0.f;
#pragma unroll 4
  for (int i = 0; i < 64; ++i) acc += sw[(g << 6) + i] * tf[(size_t)i * 128];
  if (g == 0) sacc[d] = acc;
  float e = (tid < 128) ? sw[tid] : 0.f;
  for (int off = 32; off; off >>= 1) e += __shfl_xor(e, off);
  if ((tid & 63) == 0 && tid < 128) sse[tid >> 6] = e;
  __syncthreads();
  if (g == 1) pp[bs * 132 + d] = sacc[d] + acc;
  if (tid == 0) pp[bs * 132 + 128] = sse[0] + sse[1];
}

// ---------------- softmax pool phase 2: reduce + l2 normalize ----------------
__global__ __launch_bounds__(128) void k_pool2(const float* __restrict__ pp,
    float* __restrict__ out){
  __shared__ float s2[2];
  const int b = blockIdx.x, tid = threadIdx.x;
  float num = 0.f, den = 0.f;
#pragma unroll
  for (int seg = 0; seg < 8; ++seg) {
    num += pp[(b * 8 + seg) * 132 + tid];
    den += pp[(b * 8 + seg) * 132 + 128];
  }
  float pooled = num / den;
  float sq = pooled * pooled;
  for (int off = 32; off; off >>= 1) sq += __shfl_xor(sq, off);
  if ((tid & 63) == 0) s2[tid >> 6] = sq;
  __syncthreads();
  float nrm = fmaxf(sqrtf(s2[0] + s2[1]), 1e-12f);
  out[(size_t)b * 128 + tid] = pooled / nrm;
}

extern "C" void kernel_launch(void* const* d_in, const int* in_sizes, int n_in,
                              void* d_out, int out_size, void* d_ws, size_t ws_size,
                              hipStream_t stream) {
  const float* x       = (const float*)d_in[0];
  const float* patch_w = (const float*)d_in[1];
  const float* patch_b = (const float*)d_in[2];
  const float* pe_g    = (const float*)d_in[3];
  const float* pe_b    = (const float*)d_in[4];
  const float* in_w    = (const float*)d_in[5];
  const float* conv_w  = (const float*)d_in[6];
  const float* conv_b  = (const float*)d_in[7];
  const float* dt_bias = (const float*)d_in[8];
  const float* A_log   = (const float*)d_in[9];
  const float* D_skip  = (const float*)d_in[10];
  const float* nw      = (const float*)d_in[11];
  const float* out_w   = (const float*)d_in[12];
  const float* ln_g    = (const float*)d_in[13];
  const float* ln_b    = (const float*)d_in[14];
  const float* fn_g    = (const float*)d_in[15];
  const float* fn_b    = (const float*)d_in[16];
  const float* w1      = (const float*)d_in[17];
  const float* b1      = (const float*)d_in[18];
  const float* w2      = (const float*)d_in[19];
  const float* b2      = (const float*)d_in[20];
  float* out = (float*)d_out;
  char* ws = (char*)d_ws;

  size_t off = 0;
  float* tok  = (float*)(ws + off); off += (size_t)NB * L * DM * 4;        //  8 MB
  float* zx   = (float*)(ws + off); off += (size_t)NB * L * DPROJ * 4;     // 40.5 MB
  ushort_t* xcb = (ushort_t*)(ws + off); off += (size_t)NB * L * CDIM * 2; // 12 MB
  ushort_t* ysb = (ushort_t*)(ws + off); off += (size_t)NB * L * DI * 2;   //  8 MB
  float* Scb  = (float*)(ws + off); off += (size_t)NB * NH * 16 * 2048 * 4; // 16 MB
  float* dtb  = (float*)(ws + off); off += (size_t)NB * NH * L * 4;        // 0.5 MB
  float* lcb  = (float*)(ws + off); off += (size_t)NB * NH * L * 4;        // 0.5 MB
  float* Acb  = (float*)(ws + off); off += (size_t)NB * NH * 16 * 4;       // 8 KB
  ushort_t* inwb = (ushort_t*)(ws + off); off += (size_t)4 * EPAD * 128 * 2;
  ushort_t* owb  = (ushort_t*)(ws + off); off += (size_t)4 * 128 * 256 * 2;
  ushort_t* pwb  = (ushort_t*)(ws + off); off += (size_t)128 * 768 * 2;
  float* biasin  = (float*)(ws + off); off += (size_t)4 * EPAD * 4;
  ushort_t* w1b  = (ushort_t*)(ws + off); off += (size_t)64 * 128 * 2;
  float* pp      = (float*)(ws + off); off += (size_t)128 * 132 * 4;
  float* tokF = zx;                                            // zx dead after layers
  float* scb  = (float*)(ws + (size_t)30 * 1024 * 1024);       // inside zx, past tokF

  {
    const int total = 4 * EPAD * 128 + 4 * 128 * 256 + 128 * 768 + 4 * EPAD + 64 * 128;
    k_cvt<<<(total + 255) / 256, 256, 0, stream>>>(in_w, ln_g, ln_b, out_w, nw, patch_w, w1,
                                                   inwb, owb, pwb, biasin, w1b);
  }
  k_patch<<<256, 256, 0, stream>>>(x, pwb, patch_b, pe_g, pe_b, tok);
  for (int ly = 0; ly < 4; ++ly) {
    k_inproj<<<512, 256, 0, stream>>>(tok, inwb + (size_t)ly * EPAD * 128,
                                      biasin + ly * EPAD, zx);
    k_conv<<<NB * 16 * 2, 256, 0, stream>>>(zx, conv_w + (size_t)ly * CDIM * 4,
                                            conv_b + ly * CDIM, dt_bias + ly * NH,
                                            A_log + ly * NH, xcb, dtb, lcb, Acb);
    k_cstate<<<NB * NH * 16, 256, 0, stream>>>(xcb, dtb, lcb, Scb);
    k_hscan<<<NB * NH * 8, 256, 0, stream>>>(Scb, Acb);
    k_chunky<<<NB * NH * 16, 256, 0, stream>>>(xcb, Scb, dtb, lcb,
                                               D_skip + ly * NH, ysb);
    k_gateout<<<256, 256, 0, stream>>>(zx, ysb, owb + (size_t)ly * 128 * 256, tok);
  }
  k_score<<<256, 256, 0, stream>>>(tok, fn_g, fn_b, w1b, b1, w2, b2, tokF, scb);
  k_pool1<<<128, 256, 0, stream>>>(tokF, scb, pp);
  k_pool2<<<16, 128, 0, stream>>>(pp, out);
}

// Round 10
// 430.137 us; speedup vs baseline: 1.2974x; 1.1124x over previous
//
#include <hip/hip_runtime.h>
#include <math.h>

#define EPS 1e-5f

constexpr int NB      = 16;
constexpr int L       = 1024;
constexpr int DM      = 128;
constexpr int DI      = 256;
constexpr int DS      = 64;
constexpr int NH      = 8;
constexpr int DPROJ   = 648;   // 2*DI + 2*DS + NH
constexpr int CDIM    = 384;   // DI + 2*DS
constexpr int EPAD    = 656;   // DPROJ padded to 41*16

typedef __attribute__((ext_vector_type(8))) short short8v;
typedef __attribute__((ext_vector_type(4))) short short4v;
typedef __attribute__((ext_vector_type(4))) float f32x4;
typedef unsigned short ushort_t;

__device__ __forceinline__ float silu_f(float x){ return x / (1.f + expf(-x)); }
__device__ __forceinline__ ushort_t f2bf(float f){
  union { float f; unsigned int u; } v; v.f = f;
  unsigned int r = v.u + 0x7FFF + ((v.u >> 16) & 1);
  return (ushort_t)(r >> 16);
}
__device__ __forceinline__ float bf2f(ushort_t u){
  union { float f; unsigned int u; } v; v.u = ((unsigned int)u) << 16;
  return v.f;
}
__device__ __forceinline__ short8v pack8(float4 a, float4 b){
  short8v v;
  v[0]=(short)f2bf(a.x); v[1]=(short)f2bf(a.y); v[2]=(short)f2bf(a.z); v[3]=(short)f2bf(a.w);
  v[4]=(short)f2bf(b.x); v[5]=(short)f2bf(b.y); v[6]=(short)f2bf(b.z); v[7]=(short)f2bf(b.w);
  return v;
}

// ---------------- weight conversion / folding (runs once per launch) ----------------
__global__ __launch_bounds__(256) void k_cvt(const float* __restrict__ in_w,
    const float* __restrict__ ln_g, const float* __restrict__ ln_b,
    const float* __restrict__ out_w, const float* __restrict__ nw,
    const float* __restrict__ patch_w, const float* __restrict__ w1,
    ushort_t* __restrict__ inwb, ushort_t* __restrict__ owb,
    ushort_t* __restrict__ pwb, float* __restrict__ biasin,
    ushort_t* __restrict__ w1b){
  const int R1 = 4 * EPAD * 128, R2 = 4 * 128 * 256, R3 = 128 * 768, R4 = 4 * EPAD, R5 = 64 * 128;
  int i = blockIdx.x * 256 + threadIdx.x;
  if (i < R1) {
    int ly = i / (EPAD * 128), rem = i % (EPAD * 128), e = rem >> 7, d = rem & 127;
    float v = 0.f;
    if (e < DPROJ) v = in_w[((size_t)ly * DPROJ + e) * 128 + d] * ln_g[ly * 128 + d];
    inwb[i] = f2bf(v);
    return;
  }
  i -= R1;
  if (i < R2) {
    int ly = i >> 15, rem = i & 32767, e = rem & 255;
    owb[i] = f2bf(out_w[i] * nw[ly * 256 + e]);
    return;
  }
  i -= R2;
  if (i < R3) { pwb[i] = f2bf(patch_w[i]); return; }
  i -= R3;
  if (i < R4) {
    int ly = i / EPAD, e = i % EPAD;
    float s = 0.f;
    if (e < DPROJ) {
      const float* r = in_w + ((size_t)ly * DPROJ + e) * 128;
      const float* b = ln_b + ly * 128;
      for (int d = 0; d < 128; ++d) s += r[d] * b[d];
    }
    biasin[i] = s;
    return;
  }
  i -= R4;
  if (i < R5) w1b[i] = f2bf(w1[i]);
}

// ---------------- patch embed (MFMA) + pos layernorm ----------------
__global__ __launch_bounds__(256) void k_patch(const float* __restrict__ x,
    const ushort_t* __restrict__ pwb, const float* __restrict__ pb,
    const float* __restrict__ pg, const float* __restrict__ pbe,
    float* __restrict__ tok){
  __shared__ ushort_t Al[64 * 128];
  __shared__ ushort_t Bl[128 * 128];
  __shared__ float spb[128], spg[128], spe[128];
  const int m0 = blockIdx.x * 64;
  const int tid = threadIdx.x;
  char* Ab = (char*)Al; char* Bb = (char*)Bl;
  if (tid < 128) { spb[tid] = pb[tid]; spg[tid] = pg[tid]; spe[tid] = pbe[tid]; }
  const int w = tid >> 6, l = tid & 63, lr = l & 15, lgp = l >> 4;
  f32x4 acc[8];
#pragma unroll
  for (int nt = 0; nt < 8; ++nt) acc[nt] = (f32x4){0.f, 0.f, 0.f, 0.f};
  for (int kc = 0; kc < 6; ++kc) {
    __syncthreads();
    for (int idx = tid; idx < 128 * 16; idx += 256) {
      int n = idx >> 4, ch = idx & 15;
      short8v v = *(const short8v*)(pwb + (size_t)n * 768 + kc * 128 + (ch << 3));
      *(short8v*)(Bb + n * 256 + ((ch * 16) ^ ((n & 7) << 4))) = v;
    }
    {
      const int c = kc >> 1;
      for (int i = tid; i < 1024; i += 256) {
        int t = i >> 4, p = (i >> 1) & 7, o = i & 1;
        int T = m0 + t, bb = T >> 10, tl = T & 1023, hp = tl >> 5, wp = tl & 31;
        const float* src = x + (((size_t)(bb * 3 + c) * 512 + hp * 16 + ((kc & 1) << 3) + p) * 512
                                + wp * 16 + o * 8);
        float4 f0 = *(const float4*)src;
        float4 f1 = *(const float4*)(src + 4);
        short8v v = pack8(f0, f1);
        int kk = p * 16 + o * 8;
        *(short8v*)(Ab + t * 256 + ((kk * 2) ^ ((t & 7) << 4))) = v;
      }
    }
    __syncthreads();
    short8v a[4];
#pragma unroll
    for (int ks = 0; ks < 4; ++ks)
      a[ks] = *(const short8v*)(Ab + (16 * w + lr) * 256 + ((ks * 64 + lgp * 16) ^ ((lr & 7) << 4)));
#pragma unroll
    for (int nt = 0; nt < 8; ++nt) {
#pragma unroll
      for (int ks = 0; ks < 4; ++ks) {
        short8v b = *(const short8v*)(Bb + (nt * 16 + lr) * 256 + ((ks * 64 + lgp * 16) ^ ((lr & 7) << 4)));
        acc[nt] = __builtin_amdgcn_mfma_f32_16x16x32_bf16(a[ks], b, acc[nt], 0, 0, 0);
      }
    }
  }
  float s4[4] = {0,0,0,0}, q4[4] = {0,0,0,0};
#pragma unroll
  for (int nt = 0; nt < 8; ++nt) {
    const float bb = spb[nt * 16 + lr];
#pragma unroll
    for (int r = 0; r < 4; ++r) { float v = acc[nt][r] + bb; s4[r] += v; q4[r] += v * v; }
  }
#pragma unroll
  for (int r = 0; r < 4; ++r) {
    for (int off = 1; off < 16; off <<= 1) {
      s4[r] += __shfl_xor(s4[r], off, 16);
      q4[r] += __shfl_xor(q4[r], off, 16);
    }
  }
#pragma unroll
  for (int r = 0; r < 4; ++r) {
    float mean = s4[r] * (1.f / 128.f);
    float var  = q4[r] * (1.f / 128.f) - mean * mean;
    float rstd = rsqrtf(var + EPS);
    const size_t row = (size_t)(m0 + 16 * w + lgp * 4 + r) * 128;
#pragma unroll
    for (int nt = 0; nt < 8; ++nt) {
      int col = nt * 16 + lr;
      float v = acc[nt][r] + spb[col];
      tok[row + col] = (v - mean) * rstd * spg[col] + spe[col];
    }
  }
}

// ---------------- fused layernorm + in_proj (MFMA, M=128 tile, bf16 zx out) ----------------
__global__ __launch_bounds__(256) void k_inproj(const float* __restrict__ tok,
    const ushort_t* __restrict__ inwb, const float* __restrict__ biasin,
    ushort_t* __restrict__ zxb){
  __shared__ ushort_t Al[128 * 128];
  __shared__ ushort_t Bl[176 * 128];
  __shared__ float sBias[176];
  const int blk = blockIdx.x;
  const int mb = blk >> 2, nb = blk & 3;
  const int m0 = mb << 7, n0 = nb * 176;
  const int NT = (nb == 3) ? 128 : 176;
  const int tid = threadIdx.x;
  char* Ab = (char*)Al; char* Bb = (char*)Bl;
  for (int idx = tid; idx < (NT << 4); idx += 256) {
    int row = idx >> 4, ch = idx & 15;
    short8v v = *(const short8v*)(inwb + ((size_t)(n0 + row) << 7) + (ch << 3));
    *(short8v*)(Bb + row * 256 + ((ch * 16) ^ ((row & 7) << 4))) = v;
  }
  for (int idx = tid; idx < NT; idx += 256) sBias[idx] = biasin[n0 + idx];
  for (int rp = 0; rp < 2; ++rp) {
    const int r = (rp << 6) + (tid >> 2), t4 = tid & 3;
    const float* src = tok + (((size_t)(m0 + r)) << 7) + t4 * 32;
    float v[32];
    float s = 0.f, sq = 0.f;
#pragma unroll
    for (int k = 0; k < 8; ++k) {
      float4 f = *(const float4*)(src + 4 * k);
      v[4*k] = f.x; v[4*k+1] = f.y; v[4*k+2] = f.z; v[4*k+3] = f.w;
      s += f.x + f.y + f.z + f.w;
      sq += f.x*f.x + f.y*f.y + f.z*f.z + f.w*f.w;
    }
    s  += __shfl_xor(s, 1, 4);  s  += __shfl_xor(s, 2, 4);
    sq += __shfl_xor(sq, 1, 4); sq += __shfl_xor(sq, 2, 4);
    float mean = s * (1.f / 128.f);
    float var  = sq * (1.f / 128.f) - mean * mean;
    float rstd = rsqrtf(var + EPS);
#pragma unroll
    for (int k = 0; k < 4; ++k) {
      short8v o;
#pragma unroll
      for (int e = 0; e < 8; ++e) o[e] = (short)f2bf((v[8*k + e] - mean) * rstd);
      *(short8v*)(Ab + r * 256 + ((t4 * 64 + 16 * k) ^ ((r & 7) << 4))) = o;
    }
  }
  __syncthreads();
  const int w = tid >> 6, l = tid & 63, lr = l & 15, lgp = l >> 4;
  const int xsl = (lr & 7) << 4;
  short8v a[2][4];
#pragma unroll
  for (int mi = 0; mi < 2; ++mi) {
    const int mt = w + mi * 4;
#pragma unroll
    for (int ks = 0; ks < 4; ++ks)
      a[mi][ks] = *(const short8v*)(Ab + (16 * mt + lr) * 256 + ((ks * 64 + lgp * 16) ^ xsl));
  }
  const int NTT = NT >> 4;
  for (int nt = 0; nt < NTT; ++nt) {
    f32x4 acc0 = (f32x4){0.f, 0.f, 0.f, 0.f};
    f32x4 acc1 = (f32x4){0.f, 0.f, 0.f, 0.f};
#pragma unroll
    for (int ks = 0; ks < 4; ++ks) {
      short8v b = *(const short8v*)(Bb + (nt * 16 + lr) * 256 + ((ks * 64 + lgp * 16) ^ xsl));
      acc0 = __builtin_amdgcn_mfma_f32_16x16x32_bf16(a[0][ks], b, acc0, 0, 0, 0);
      acc1 = __builtin_amdgcn_mfma_f32_16x16x32_bf16(a[1][ks], b, acc1, 0, 0, 0);
    }
    const int col = n0 + nt * 16 + lr;
    if (col < DPROJ) {
      const float bias = sBias[nt * 16 + lr];
#pragma unroll
      for (int r = 0; r < 4; ++r) {
        zxb[((size_t)(m0 + 16 * w       + lgp * 4 + r)) * DPROJ + col] = f2bf(acc0[r] + bias);
        zxb[((size_t)(m0 + 16 * (w + 4) + lgp * 4 + r)) * DPROJ + col] = f2bf(acc1[r] + bias);
      }
    }
  }
}

// ---------------- causal depthwise conv + silu (bf16 in/out) + fused dt cumsum ----------------
constexpr int CONVC = 192;
__global__ __launch_bounds__(256) void k_conv(const ushort_t* __restrict__ zxb,
    const float* __restrict__ cw, const float* __restrict__ cb,
    const float* __restrict__ dtbias, const float* __restrict__ Alog,
    ushort_t* __restrict__ xc, float* __restrict__ dtb,
    float* __restrict__ lcb, float* __restrict__ Acb){
  __shared__ float st[67][CONVC];
  __shared__ float swt[CONVC][4];
  __shared__ float sbias[CONVC];
  const int blk = blockIdx.x;
  const int cg = blk & 1, tile = (blk >> 1) & 15, b = blk >> 5;
  const int l0 = tile << 6, ch0 = cg * CONVC;
  const int tid = threadIdx.x;
  for (int i = tid; i < CONVC; i += 256) {
    float4 wv = *(const float4*)(cw + (size_t)(ch0 + i) * 4);
    swt[i][0] = wv.x; swt[i][1] = wv.y; swt[i][2] = wv.z; swt[i][3] = wv.w;
    sbias[i] = cb[ch0 + i];
  }
  for (int i = tid; i < 67 * 24; i += 256) {
    int rr = i / 24, g = i % 24;
    int lrow = l0 + rr - 3;
    float v[8] = {0,0,0,0,0,0,0,0};
    if (lrow >= 0) {
      short8v z8 = *(const short8v*)(zxb + ((size_t)(b << 10) + lrow) * DPROJ + DI + ch0 + g * 8);
#pragma unroll
      for (int j = 0; j < 8; ++j) v[j] = bf2f((ushort_t)z8[j]);
    }
    *(float4*)(&st[rr][g * 8])     = make_float4(v[0], v[1], v[2], v[3]);
    *(float4*)(&st[rr][g * 8 + 4]) = make_float4(v[4], v[5], v[6], v[7]);
  }
  // fused dt: 4 waves x 2 heads each, lanes = tokens of this chunk
  if (cg == 0) {
    const int wv = tid >> 6, lane = tid & 63;
#pragma unroll
    for (int i = 0; i < 2; ++i) {
      const int hh = wv * 2 + i;
      float raw = bf2f(zxb[((size_t)(b << 10) + l0 + lane) * DPROJ + 640 + hh]) + dtbias[hh];
      float dt = raw > 20.f ? raw : log1pf(expf(raw));
      float cum = dt * (-expf(Alog[hh]));
      for (int off = 1; off < 64; off <<= 1) {
        float v = __shfl_up(cum, off, 64);
        if (lane >= off) cum += v;
      }
      size_t o = ((size_t)((b << 3) + hh) << 10) + l0 + lane;
      dtb[o] = dt; lcb[o] = cum;
      if (lane == 63) Acb[((b << 3) + hh) * 16 + tile] = expf(cum);
    }
  }
  __syncthreads();
  for (int i = tid; i < 64 * 48; i += 256) {
    int t = i / 48, g = i % 48;
    short4v ov;
#pragma unroll
    for (int j = 0; j < 4; ++j) {
      int c2 = g * 4 + j;
      float acc = sbias[c2] + st[t][c2] * swt[c2][0] + st[t+1][c2] * swt[c2][1]
                + st[t+2][c2] * swt[c2][2] + st[t+3][c2] * swt[c2][3];
      ov[j] = (short)f2bf(silu_f(acc));
    }
    *(short4v*)(xc + ((size_t)(b << 10) + l0 + t) * CDIM + ch0 + g * 4) = ov;
  }
}

// ---------------- SSD step 2: per-chunk state S_c (MFMA, bf16 in, bf16 out) ----------------
__global__ __launch_bounds__(256) void k_cstate(const ushort_t* __restrict__ xc,
    const float* __restrict__ dtb, const float* __restrict__ lcb,
    ushort_t* __restrict__ Sc){
  __shared__ ushort_t sXc[32 * 64];   // A_op [p][s]
  __shared__ ushort_t sBt[64 * 64];   // B_op [n][s]
  __shared__ float scoef[64];
  const int blk = blockIdx.x;
  const int c = blk & 15, h = (blk >> 4) & 7, b = blk >> 7;
  const int tid = threadIdx.x;
  const int l0 = c << 6;
  char* pA = (char*)sXc; char* pB = (char*)sBt;
  const size_t obh = ((size_t)((b << 3) + h) << 10) + l0;
  if (tid < 64) {
    float lcT = lcb[obh + 63];
    scoef[tid] = dtb[obh + tid] * __expf(fminf(lcT - lcb[obh + tid], 0.f));
  }
  const int s = tid >> 2, q = tid & 3;
  const ushort_t* xr = xc + ((size_t)(b << 10) + l0 + s) * CDIM;
  short8v b0 = *(const short8v*)(xr + 256 + q * 16);
  short8v b1 = *(const short8v*)(xr + 256 + q * 16 + 8);
  short8v x8 = *(const short8v*)(xr + (h << 5) + q * 8);
#pragma unroll
  for (int j = 0; j < 16; ++j) {
    const int n = q * 16 + j;
    ushort_t bv = (ushort_t)(j < 8 ? b0[j] : b1[j - 8]);
    *(ushort_t*)(pB + n * 128 + ((s * 2) ^ ((n & 7) << 4))) = bv;
  }
  __syncthreads();
  const float cf = scoef[s];
#pragma unroll
  for (int j = 0; j < 8; ++j) {
    const int p = q * 8 + j;
    *(ushort_t*)(pA + p * 128 + ((s * 2) ^ ((p & 7) << 4))) = f2bf(cf * bf2f((ushort_t)x8[j]));
  }
  __syncthreads();
  const int w = tid >> 6, l = tid & 63, lr = l & 15, lgp = l >> 4;
  const int xsl = (lr & 7) << 4;
  const int pt = w & 1, ng = w >> 1;
  short8v a0 = *(const short8v*)(pA + (pt * 16 + lr) * 128 + ((lgp * 16) ^ xsl));
  short8v a1 = *(const short8v*)(pA + (pt * 16 + lr) * 128 + ((64 + lgp * 16) ^ xsl));
  ushort_t* dst = Sc + ((size_t)blk << 11);
#pragma unroll
  for (int ni = 0; ni < 2; ++ni) {
    const int nt = ng * 2 + ni;
    f32x4 acc = (f32x4){0.f, 0.f, 0.f, 0.f};
    short8v bb0 = *(const short8v*)(pB + (nt * 16 + lr) * 128 + ((lgp * 16) ^ xsl));
    short8v bb1 = *(const short8v*)(pB + (nt * 16 + lr) * 128 + ((64 + lgp * 16) ^ xsl));
    acc = __builtin_amdgcn_mfma_f32_16x16x32_bf16(a0, bb0, acc, 0, 0, 0);
    acc = __builtin_amdgcn_mfma_f32_16x16x32_bf16(a1, bb1, acc, 0, 0, 0);
#pragma unroll
    for (int r = 0; r < 4; ++r)
      dst[(pt * 16 + lgp * 4 + r) * 64 + nt * 16 + lr] = f2bf(acc[r]);
  }
}

// ---------------- SSD step 3: inter-chunk scan (bf16 storage, fp32 accumulate) ----------------
__global__ __launch_bounds__(256) void k_hscan(ushort_t* __restrict__ Sc, const float* __restrict__ Acb){
  const int blk = blockIdx.x;
  const int bh = blk >> 3;
  const int e = ((blk & 7) << 8) + threadIdx.x;
  float hs = 0.f;
  const size_t base = ((size_t)bh << 15) + e;
  for (int c = 0; c < 16; ++c) {
    const size_t o = base + ((size_t)c << 11);
    float v = bf2f(Sc[o]);
    Sc[o] = f2bf(hs);
    hs = Acb[(bh << 4) + c] * hs + v;
  }
}

// ---------------- SSD step 4: within-chunk outputs — full MFMA (bf16 in/out) ----------------
__global__ __launch_bounds__(256) void k_chunky(const ushort_t* __restrict__ xc,
    const ushort_t* __restrict__ h0buf, const float* __restrict__ dtb,
    const float* __restrict__ lcb, const float* __restrict__ Dsk,
    ushort_t* __restrict__ ys){
  __shared__ ushort_t sC[64 * 64];
  __shared__ ushort_t sBm[64 * 64];
  __shared__ ushort_t sAW[64 * 128];
  __shared__ ushort_t sBX[32 * 128];
  __shared__ float sXT[32][65];
  __shared__ float sdt[64], slc[64];
  const int blk = blockIdx.x;
  const int c = blk & 15, h = (blk >> 4) & 7, b = blk >> 7;
  const int tid = threadIdx.x;
  const int l0 = c << 6;
  char* pC = (char*)sC; char* pB = (char*)sBm; char* pA = (char*)sAW; char* pX = (char*)sBX;
  const size_t obh = ((size_t)((b << 3) + h) << 10) + l0;
  if (tid < 64) { sdt[tid] = dtb[obh + tid]; slc[tid] = lcb[obh + tid]; }
  {
    const int row = tid >> 2, q = tid & 3;
    const ushort_t* xr = xc + ((size_t)(b << 10) + l0 + row) * CDIM;
    const int xs = (row & 7) << 4;
    short8v b0 = *(const short8v*)(xr + 256 + q * 16);
    short8v b1 = *(const short8v*)(xr + 256 + q * 16 + 8);
    *(short8v*)(pB + row * 128 + ((q * 32) ^ xs))      = b0;
    *(short8v*)(pB + row * 128 + ((q * 32 + 16) ^ xs)) = b1;
    short8v c0 = *(const short8v*)(xr + 320 + q * 16);
    short8v c1 = *(const short8v*)(xr + 320 + q * 16 + 8);
    *(short8v*)(pC + row * 128 + ((q * 32) ^ xs))      = c0;
    *(short8v*)(pC + row * 128 + ((q * 32 + 16) ^ xs)) = c1;
    const float Pt = __expf(lcb[obh + row]);
    short8v q0, q1;
#pragma unroll
    for (int j = 0; j < 8; ++j) {
      q0[j] = (short)f2bf(Pt * bf2f((ushort_t)c0[j]));
      q1[j] = (short)f2bf(Pt * bf2f((ushort_t)c1[j]));
    }
    *(short8v*)(pA + row * 256 + ((128 + q * 32) ^ xs))      = q0;
    *(short8v*)(pA + row * 256 + ((128 + q * 32 + 16) ^ xs)) = q1;
    short8v x8 = *(const short8v*)(xr + (h << 5) + q * 8);
#pragma unroll
    for (int j = 0; j < 8; ++j) sXT[q * 8 + j][row] = bf2f((ushort_t)x8[j]);
  }
  {
    const int p = tid >> 3, n8 = (tid & 7) << 3;
    short8v h8 = *(const short8v*)(h0buf + ((size_t)blk << 11) + (p << 6) + n8);
    *(short8v*)(pX + p * 256 + (((64 + n8) * 2) ^ ((p & 7) << 4))) = h8;
  }
  __syncthreads();
  {
    const int p = tid >> 3, s8 = (tid & 7) << 3;
    short8v vx;
#pragma unroll
    for (int e = 0; e < 8; ++e) vx[e] = (short)f2bf(sXT[p][s8 + e]);
    *(short8v*)(pX + p * 256 + ((s8 * 2) ^ ((p & 7) << 4))) = vx;
  }
  const int w = tid >> 6, l = tid & 63, lr = l & 15, lgp = l >> 4;
  const int xsl = (lr & 7) << 4;
  f32x4 accg[4];
#pragma unroll
  for (int nt = 0; nt < 4; ++nt) accg[nt] = (f32x4){0.f, 0.f, 0.f, 0.f};
  {
    short8v a0 = *(const short8v*)(pC + (16 * w + lr) * 128 + ((lgp * 16) ^ xsl));
    short8v a1 = *(const short8v*)(pC + (16 * w + lr) * 128 + ((64 + lgp * 16) ^ xsl));
#pragma unroll
    for (int nt = 0; nt < 4; ++nt) {
      short8v b0 = *(const short8v*)(pB + (nt * 16 + lr) * 128 + ((lgp * 16) ^ xsl));
      short8v b1 = *(const short8v*)(pB + (nt * 16 + lr) * 128 + ((64 + lgp * 16) ^ xsl));
      accg[nt] = __builtin_amdgcn_mfma_f32_16x16x32_bf16(a0, b0, accg[nt], 0, 0, 0);
      accg[nt] = __builtin_amdgcn_mfma_f32_16x16x32_bf16(a1, b1, accg[nt], 0, 0, 0);
    }
  }
#pragma unroll
  for (int nt = 0; nt < 4; ++nt) {
    const int s = nt * 16 + lr;
    const float ds = sdt[s], ls = slc[s];
#pragma unroll
    for (int r = 0; r < 4; ++r) {
      const int t = 16 * w + lgp * 4 + r;
      float wv = 0.f;
      if (s <= t) wv = ds * __expf(fminf(slc[t] - ls, 0.f)) * accg[nt][r];
      *(ushort_t*)(pA + t * 256 + ((s * 2) ^ ((t & 7) << 4))) = f2bf(wv);
    }
  }
  __syncthreads();
  f32x4 accy[2];
  accy[0] = (f32x4){0.f, 0.f, 0.f, 0.f};
  accy[1] = (f32x4){0.f, 0.f, 0.f, 0.f};
  short8v aw[4];
#pragma unroll
  for (int ks = 0; ks < 4; ++ks)
    aw[ks] = *(const short8v*)(pA + (16 * w + lr) * 256 + ((ks * 64 + lgp * 16) ^ xsl));
#pragma unroll
  for (int nt = 0; nt < 2; ++nt) {
#pragma unroll
    for (int ks = 0; ks < 4; ++ks) {
      short8v bx = *(const short8v*)(pX + (nt * 16 + lr) * 256 + ((ks * 64 + lgp * 16) ^ xsl));
      accy[nt] = __builtin_amdgcn_mfma_f32_16x16x32_bf16(aw[ks], bx, accy[nt], 0, 0, 0);
    }
  }
  const float dsk = Dsk[h];
#pragma unroll
  for (int nt = 0; nt < 2; ++nt) {
    const int p = nt * 16 + lr;
#pragma unroll
    for (int r = 0; r < 4; ++r) {
      const int t = 16 * w + lgp * 4 + r;
      ys[((size_t)(b << 10) + l0 + t) * DI + (h << 5) + p] = f2bf(accy[nt][r] + dsk * sXT[p][t]);
    }
  }
}

// ---------------- gate*silu(z), RMSNorm, out_proj (MFMA, dbuf B), residual add ----------------
__global__ __launch_bounds__(256) void k_gateout(const ushort_t* __restrict__ zxb,
    const ushort_t* __restrict__ ysb, const ushort_t* __restrict__ owb,
    float* __restrict__ tok){
  __shared__ ushort_t Al[64 * 256];
  __shared__ ushort_t Bl[2][128 * 64];
  const int m0 = blockIdx.x * 64;
  const int tid = threadIdx.x;
  char* Ab = (char*)Al;
  {
    const int r = tid >> 2, t4 = tid & 3;
    const size_t row = (size_t)(m0 + r);
    const ushort_t* yp = ysb + row * 256 + t4 * 64;
    const ushort_t* zp = zxb + row * DPROJ + t4 * 64;
    float p[64];
    float sq = 0.f;
#pragma unroll
    for (int k = 0; k < 8; ++k) {
      short8v y8 = *(const short8v*)(yp + 8 * k);
      short8v z8 = *(const short8v*)(zp + 8 * k);
#pragma unroll
      for (int j = 0; j < 8; ++j) {
        float zz = bf2f((ushort_t)z8[j]);
        float a = bf2f((ushort_t)y8[j]) * (zz / (1.f + __expf(-zz)));
        p[8 * k + j] = a; sq += a * a;
      }
    }
    sq += __shfl_xor(sq, 1, 4); sq += __shfl_xor(sq, 2, 4);
    float rstd = rsqrtf(sq * (1.f / 256.f) + EPS);
#pragma unroll
    for (int k = 0; k < 8; ++k) {
      short8v o;
#pragma unroll
      for (int e = 0; e < 8; ++e) o[e] = (short)f2bf(p[8*k + e] * rstd);
      *(short8v*)(Ab + r * 512 + ((t4 * 128 + 16 * k) ^ ((r & 7) << 4))) = o;
    }
  }
  // preload B chunk 0 into registers
  short8v breg[4];
#pragma unroll
  for (int j = 0; j < 4; ++j) {
    int idx = tid + 256 * j, row = idx >> 3, ch = idx & 7;
    breg[j] = *(const short8v*)(owb + ((size_t)row << 8) + (ch << 3));
  }
  const int w = tid >> 6, l = tid & 63, lr = l & 15, lgp = l >> 4;
  f32x4 acc[8];
#pragma unroll
  for (int nt = 0; nt < 8; ++nt) acc[nt] = (f32x4){0.f, 0.f, 0.f, 0.f};
  int buf = 0;
  for (int kq = 0; kq < 4; ++kq) {
    char* Bb = (char*)Bl[buf];
#pragma unroll
    for (int j = 0; j < 4; ++j) {
      int idx = tid + 256 * j, row = idx >> 3, ch = idx & 7;
      *(short8v*)(Bb + row * 128 + ((ch * 16) ^ ((row & 7) << 4))) = breg[j];
    }
    __syncthreads();
    if (kq < 3) {
#pragma unroll
      for (int j = 0; j < 4; ++j) {
        int idx = tid + 256 * j, row = idx >> 3, ch = idx & 7;
        breg[j] = *(const short8v*)(owb + ((size_t)row << 8) + (kq + 1) * 64 + (ch << 3));
      }
    }
    short8v a0 = *(const short8v*)(Ab + (16*w + lr) * 512 + ((kq * 128 +      lgp * 16) ^ ((lr & 7) << 4)));
    short8v a1 = *(const short8v*)(Ab + (16*w + lr) * 512 + ((kq * 128 + 64 + lgp * 16) ^ ((lr & 7) << 4)));
#pragma unroll
    for (int nt = 0; nt < 8; ++nt) {
      short8v b0 = *(const short8v*)(Bb + (nt * 16 + lr) * 128 + ((     lgp * 16) ^ ((lr & 7) << 4)));
      short8v b1 = *(const short8v*)(Bb + (nt * 16 + lr) * 128 + ((64 + lgp * 16) ^ ((lr & 7) << 4)));
      acc[nt] = __builtin_amdgcn_mfma_f32_16x16x32_bf16(a0, b0, acc[nt], 0, 0, 0);
      acc[nt] = __builtin_amdgcn_mfma_f32_16x16x32_bf16(a1, b1, acc[nt], 0, 0, 0);
    }
    buf ^= 1;
  }
#pragma unroll
  for (int nt = 0; nt < 8; ++nt) {
#pragma unroll
    for (int r = 0; r < 4; ++r) {
      tok[((size_t)(m0 + 16 * w + lgp * 4 + r)) * 128 + nt * 16 + lr] += acc[nt][r];
    }
  }
}

// ---------------- final LN + attention scores (MFMA) ----------------
__global__ __launch_bounds__(256) void k_score(const float* __restrict__ tok,
    const float* __restrict__ fg, const float* __restrict__ fb,
    const ushort_t* __restrict__ w1b, const float* __restrict__ b1,
    const float* __restrict__ w2, const float* __restrict__ b2,
    float* __restrict__ tokF, float* __restrict__ sc){
  __shared__ ushort_t Al[64 * 128];
  __shared__ ushort_t Wl[64 * 128];
  __shared__ float sb1[64], sw2[64];
  const int m0 = blockIdx.x * 64;
  const int tid = threadIdx.x;
  char* Ab = (char*)Al; char* Wb = (char*)Wl;
  for (int idx = tid; idx < 64 * 16; idx += 256) {
    int row = idx >> 4, ch = idx & 15;
    short8v v = *(const short8v*)(w1b + (row << 7) + (ch << 3));
    *(short8v*)(Wb + row * 256 + ((ch * 16) ^ ((row & 7) << 4))) = v;
  }
  if (tid < 64) { sb1[tid] = b1[tid]; sw2[tid] = w2[tid]; }
  {
    const int r = tid >> 2, t4 = tid & 3;
    const float* src = tok + (((size_t)(m0 + r)) << 7) + t4 * 32;
    float v[32];
    float s = 0.f, sq = 0.f;
#pragma unroll
    for (int k = 0; k < 8; ++k) {
      float4 f = *(const float4*)(src + 4 * k);
      v[4*k] = f.x; v[4*k+1] = f.y; v[4*k+2] = f.z; v[4*k+3] = f.w;
      s += f.x + f.y + f.z + f.w;
      sq += f.x*f.x + f.y*f.y + f.z*f.z + f.w*f.w;
    }
    s  += __shfl_xor(s, 1, 4);  s  += __shfl_xor(s, 2, 4);
    sq += __shfl_xor(sq, 1, 4); sq += __shfl_xor(sq, 2, 4);
    float mean = s * (1.f / 128.f);
    float var  = sq * (1.f / 128.f) - mean * mean;
    float rstd = rsqrtf(var + EPS);
    float* tdst = tokF + (((size_t)(m0 + r)) << 7) + t4 * 32;
#pragma unroll
    for (int k = 0; k < 4; ++k) {
      float o8[8];
      float4 g0 = *(const float4*)(fg + t4 * 32 + 8 * k);
      float4 g1 = *(const float4*)(fg + t4 * 32 + 8 * k + 4);
      float4 e0 = *(const float4*)(fb + t4 * 32 + 8 * k);
      float4 e1 = *(const float4*)(fb + t4 * 32 + 8 * k + 4);
      o8[0] = (v[8*k+0]-mean)*rstd*g0.x + e0.x; o8[1] = (v[8*k+1]-mean)*rstd*g0.y + e0.y;
      o8[2] = (v[8*k+2]-mean)*rstd*g0.z + e0.z; o8[3] = (v[8*k+3]-mean)*rstd*g0.w + e0.w;
      o8[4] = (v[8*k+4]-mean)*rstd*g1.x + e1.x; o8[5] = (v[8*k+5]-mean)*rstd*g1.y + e1.y;
      o8[6] = (v[8*k+6]-mean)*rstd*g1.z + e1.z; o8[7] = (v[8*k+7]-mean)*rstd*g1.w + e1.w;
      *(float4*)(tdst + 8*k)     = make_float4(o8[0], o8[1], o8[2], o8[3]);
      *(float4*)(tdst + 8*k + 4) = make_float4(o8[4], o8[5], o8[6], o8[7]);
      short8v ov;
#pragma unroll
      for (int e = 0; e < 8; ++e) ov[e] = (short)f2bf(o8[e]);
      *(short8v*)(Ab + r * 256 + ((t4 * 64 + 16 * k) ^ ((r & 7) << 4))) = ov;
    }
  }
  __syncthreads();
  const int w = tid >> 6, l = tid & 63, lr = l & 15, lgp = l >> 4;
  const int xsl = (lr & 7) << 4;
  short8v a[4];
#pragma unroll
  for (int ks = 0; ks < 4; ++ks)
    a[ks] = *(const short8v*)(Ab + (16 * w + lr) * 256 + ((ks * 64 + lgp * 16) ^ xsl));
  float sacc[4] = {0.f, 0.f, 0.f, 0.f};
#pragma unroll
  for (int nt = 0; nt < 4; ++nt) {
    f32x4 acc = (f32x4){0.f, 0.f, 0.f, 0.f};
#pragma unroll
    for (int ks = 0; ks < 4; ++ks) {
      short8v bb = *(const short8v*)(Wb + (nt * 16 + lr) * 256 + ((ks * 64 + lgp * 16) ^ xsl));
      acc = __builtin_amdgcn_mfma_f32_16x16x32_bf16(a[ks], bb, acc, 0, 0, 0);
    }
    const float bias = sb1[nt * 16 + lr], wv = sw2[nt * 16 + lr];
#pragma unroll
    for (int r = 0; r < 4; ++r) sacc[r] += tanhf(acc[r] + bias) * wv;
  }
#pragma unroll
  for (int r = 0; r < 4; ++r) {
    for (int off = 1; off < 16; off <<= 1) sacc[r] += __shfl_xor(sacc[r], off, 16);
  }
  if (lr == 0) {
    const float bb2 = b2[0];
#pragma unroll
    for (int r = 0; r < 4; ++r) sc[m0 + 16 * w + lgp * 4 + r] = sacc[r] + bb2;
  }
}

// ---------------- softmax pool phase 1: per-segment partials ----------------
__global__ __launch_bounds__(256) void k_pool1(const float* __restrict__ tokF,
    const float* __restrict__ sc, float* __restrict__ pp){
  __shared__ float sw[128];
  __shared__ float sacc[128];
  __shared__ float sse[2];
  const int bs = blockIdx.x, b = bs >> 3, seg = bs & 7, tid = threadIdx.x;
  const int l0 = (b << 10) + (seg << 7);
  if (tid < 128) sw[tid] = __expf(sc[l0 + tid]);
  __syncthreads();
  const int d = tid & 127, g = tid >> 7;
  const float* tf = tokF + ((size_t)(l0 + (g << 6))) * 128 + d;
  float acc = 0.f;
#pragma unroll 4
  for (int i = 0; i < 64; ++i) acc += sw[(g << 6) + i] * tf[(size_t)i * 128];
  if (g == 0) sacc[d] = acc;
  float e = (tid < 128) ? sw[tid] : 0.f;
  for (int off = 32; off; off >>= 1) e += __shfl_xor(e, off);
  if ((tid & 63) == 0 && tid < 128) sse[tid >> 6] = e;
  __syncthreads();
  if (g == 1) pp[bs * 132 + d] = sacc[d] + acc;
  if (tid == 0) pp[bs * 132 + 128] = sse[0] + sse[1];
}

// ---------------- softmax pool phase 2: reduce + l2 normalize ----------------
__global__ __launch_bounds__(128) void k_pool2(const float* __restrict__ pp,
    float* __restrict__ out){
  __shared__ float s2[2];
  const int b = blockIdx.x, tid = threadIdx.x;
  float num = 0.f, den = 0.f;
#pragma unroll
  for (int seg = 0; seg < 8; ++seg) {
    num += pp[(b * 8 + seg) * 132 + tid];
    den += pp[(b * 8 + seg) * 132 + 128];
  }
  float pooled = num / den;
  float sq = pooled * pooled;
  for (int off = 32; off; off >>= 1) sq += __shfl_xor(sq, off);
  if ((tid & 63) == 0) s2[tid >> 6] = sq;
  __syncthreads();
  float nrm = fmaxf(sqrtf(s2[0] + s2[1]), 1e-12f);
  out[(size_t)b * 128 + tid] = pooled / nrm;
}

extern "C" void kernel_launch(void* const* d_in, const int* in_sizes, int n_in,
                              void* d_out, int out_size, void* d_ws, size_t ws_size,
                              hipStream_t stream) {
  const float* x       = (const float*)d_in[0];
  const float* patch_w = (const float*)d_in[1];
  const float* patch_b = (const float*)d_in[2];
  const float* pe_g    = (const float*)d_in[3];
  const float* pe_b    = (const float*)d_in[4];
  const float* in_w    = (const float*)d_in[5];
  const float* conv_w  = (const float*)d_in[6];
  const float* conv_b  = (const float*)d_in[7];
  const float* dt_bias = (const float*)d_in[8];
  const float* A_log   = (const float*)d_in[9];
  const float* D_skip  = (const float*)d_in[10];
  const float* nw      = (const float*)d_in[11];
  const float* out_w   = (const float*)d_in[12];
  const float* ln_g    = (const float*)d_in[13];
  const float* ln_b    = (const float*)d_in[14];
  const float* fn_g    = (const float*)d_in[15];
  const float* fn_b    = (const float*)d_in[16];
  const float* w1      = (const float*)d_in[17];
  const float* b1      = (const float*)d_in[18];
  const float* w2      = (const float*)d_in[19];
  const float* b2      = (const float*)d_in[20];
  float* out = (float*)d_out;
  char* ws = (char*)d_ws;

  size_t off = 0;
  float* tok  = (float*)(ws + off); off += (size_t)NB * L * DM * 4;          //  8 MB
  ushort_t* zxb = (ushort_t*)(ws + off); off += (size_t)NB * L * DPROJ * 2;  // 20.25 MB
  ushort_t* xcb = (ushort_t*)(ws + off); off += (size_t)NB * L * CDIM * 2;   // 12 MB
  ushort_t* ysb = (ushort_t*)(ws + off); off += (size_t)NB * L * DI * 2;     //  8 MB
  ushort_t* Scb = (ushort_t*)(ws + off); off += (size_t)NB * NH * 16 * 2048 * 2; // 8 MB
  float* dtb  = (float*)(ws + off); off += (size_t)NB * NH * L * 4;          // 0.5 MB
  float* lcb  = (float*)(ws + off); off += (size_t)NB * NH * L * 4;          // 0.5 MB
  float* Acb  = (float*)(ws + off); off += (size_t)NB * NH * 16 * 4;         // 8 KB
  ushort_t* inwb = (ushort_t*)(ws + off); off += (size_t)4 * EPAD * 128 * 2;
  ushort_t* owb  = (ushort_t*)(ws + off); off += (size_t)4 * 128 * 256 * 2;
  ushort_t* pwb  = (ushort_t*)(ws + off); off += (size_t)128 * 768 * 2;
  float* biasin  = (float*)(ws + off); off += (size_t)4 * EPAD * 4;
  ushort_t* w1b  = (ushort_t*)(ws + off); off += (size_t)64 * 128 * 2;
  float* pp      = (float*)(ws + off); off += (size_t)128 * 132 * 4;
  // zxb region spans [8 MB, 28.25 MB); tokF takes [8,16), scb at 17 MB
  float* tokF = (float*)(ws + (size_t)8 * 1024 * 1024);
  float* scb  = (float*)(ws + (size_t)17 * 1024 * 1024);

  {
    const int total = 4 * EPAD * 128 + 4 * 128 * 256 + 128 * 768 + 4 * EPAD + 64 * 128;
    k_cvt<<<(total + 255) / 256, 256, 0, stream>>>(in_w, ln_g, ln_b, out_w, nw, patch_w, w1,
                                                   inwb, owb, pwb, biasin, w1b);
  }
  k_patch<<<256, 256, 0, stream>>>(x, pwb, patch_b, pe_g, pe_b, tok);
  for (int ly = 0; ly < 4; ++ly) {
    k_inproj<<<512, 256, 0, stream>>>(tok, inwb + (size_t)ly * EPAD * 128,
                                      biasin + ly * EPAD, zxb);
    k_conv<<<NB * 16 * 2, 256, 0, stream>>>(zxb, conv_w + (size_t)ly * CDIM * 4,
                                            conv_b + ly * CDIM, dt_bias + ly * NH,
                                            A_log + ly * NH, xcb, dtb, lcb, Acb);
    k_cstate<<<NB * NH * 16, 256, 0, stream>>>(xcb, dtb, lcb, Scb);
    k_hscan<<<NB * NH * 8, 256, 0, stream>>>(Scb, Acb);
    k_chunky<<<NB * NH * 16, 256, 0, stream>>>(xcb, Scb, dtb, lcb,
                                               D_skip + ly * NH, ysb);
    k_gateout<<<256, 256, 0, stream>>>(zxb, ysb, owb + (size_t)ly * 128 * 256, tok);
  }
  k_score<<<256, 256, 0, stream>>>(tok, fn_g, fn_b, w1b, b1, w2, b2, tokF, scb);
  k_pool1<<<128, 256, 0, stream>>>(tokF, scb, pp);
  k_pool2<<<16, 128, 0, stream>>>(pp, out);
}